// Round 3
// baseline (690.835 us; speedup 1.0000x reference)
//
#include <hip/hip_runtime.h>
#include <hip/hip_cooperative_groups.h>
#include <math.h>

namespace cg = cooperative_groups;

// Problem constants
constexpr int Uc = 512;
constexpr int Pc = 1024;
constexpr int Dc = 128;
constexpr int Hc = 256;
constexpr int Ec = 98304;
constexpr int Nc = 1536;   // U + P
constexpr int CAP = 192;   // bucket capacity (deg ~ B(98304,1/1536): mu=64, sigma=8)

__device__ __forceinline__ void fma4(float4& a, float n, const float4 r) {
    a.x += n * r.x; a.y += n * r.y; a.z += n * r.z; a.w += n * r.w;
}

// Shared-memory union: one allocation reused across fused phases (19.5 KB).
union __align__(16) SharedU {
    struct {   // layer 0 (D=128)
        const float* sptr[2][CAP];
        float snrm[2][CAP];
        float pagg[4][Dc];
        float aggT[Dc][2];
        float red[4][2][Hc];
    } l0;
    struct {   // hidden layers (H=256)
        int sidx[2][CAP];
        float snrm[2][CAP];
        float pagg[4][Hc];
        float aggT[Hc][2];
        float xlocT[Hc][2];
        float red[4][2][Hc];
    } lh;
    struct {   // predictor
        float auS[Hc * 8];
    } pr;
};

// ---------------- GEMM core: 16 rows x 32 cols / 256-thread block ----------------
template <int K>
__device__ __forceinline__ void gemm_core16(const float* __restrict__ xr,
                                            const float* __restrict__ wc, int M,
                                            float& acc0, float& acc1) {
#pragma unroll 4
    for (int k = 0; k < K; k += 4) {
        float4 a = *(const float4*)(xr + k);
        float2 b0 = *(const float2*)(wc + (size_t)k * M);
        float2 b1 = *(const float2*)(wc + (size_t)(k + 1) * M);
        float2 b2 = *(const float2*)(wc + (size_t)(k + 2) * M);
        float2 b3 = *(const float2*)(wc + (size_t)(k + 3) * M);
        acc0 += a.x * b0.x; acc1 += a.x * b0.y;
        acc0 += a.y * b1.x; acc1 += a.y * b1.y;
        acc0 += a.z * b2.x; acc1 += a.z * b2.y;
        acc0 += a.w * b3.x; acc1 += a.w * b3.y;
    }
}

// ---------------- front phase: scatter | weight collapse | bias ----------------
__device__ __forceinline__ void phase_front(
        int b, int t,
        const int* __restrict__ e_src, const int* __restrict__ e_dst,
        int* __restrict__ cnt, int* __restrict__ colF,
        const float* __restrict__ Wu, const float* __restrict__ Wp,
        const float* __restrict__ Wq1, const float* __restrict__ bu,
        const float* __restrict__ bp, const float* __restrict__ bq1,
        float* __restrict__ Wup, float* __restrict__ Wpp,
        float* __restrict__ bvu, float* __restrict__ bvp) {
    if (b < 384) {
        int e = b * 256 + t;
        int d = e_dst[e];
        int pos = atomicAdd(&cnt[d], 1);
        if (pos < CAP) colF[d * CAP + pos] = e_src[e];
    } else if (b < 640) {
        int id = b - 384;
        int z = id >> 7, tile = id & 127;
        int tx = t & 15, ty = t >> 4;
        const float* X = z ? Wp : Wu;
        const float* W = Wq1 + (z ? (size_t)Dc * Hc : 0);
        float* Y = z ? Wpp : Wup;
        int row = (tile >> 3) * 16 + ty, col = (tile & 7) * 32 + tx * 2;
        float a0 = 0.f, a1 = 0.f;
        gemm_core16<Dc>(X + (size_t)row * Dc, W + col, Hc, a0, a1);
        *(float2*)&Y[(size_t)row * Hc + col] = make_float2(a0, a1);
    } else if (b == 640) {
        float s = bq1[t];
#pragma unroll 8
        for (int d = 0; d < Dc; d++) s += bu[d] * Wq1[d * Hc + t];
        bvu[t] = s;
    } else if (b == 641) {
        float s = 0.f;
#pragma unroll 8
        for (int d = 0; d < Dc; d++) s += bp[d] * Wq1[(Dc + d) * Hc + t];
        bvp[t] = s;
    }
}

// ---------------- layer 0 phase: agg(embeddings) @ W0 + b0, relu -> xA ---------
// 2 nodes / block (768 blocks). Waves (2r, 2r+1) aggregate node r over neighbor
// halves; lane l -> features 2l..2l+2 (D=128). GEMV wave-k-split, float4 W.
__device__ void phase_l0(SharedU& su, int b, int t,
        const int* __restrict__ uid, const int* __restrict__ pid,
        const float* __restrict__ ue, const float* __restrict__ pe,
        const float* __restrict__ W0, const float* __restrict__ b0,
        const int* __restrict__ cnt, const int* __restrict__ colF,
        float* __restrict__ out) {
    int ibase = b * 2;
    int c[2]; float di[2];
#pragma unroll
    for (int r = 0; r < 2; r++) {
        c[r] = cnt[ibase + r];
        di[r] = rsqrtf((float)(c[r] + 1));
        int deg = min(c[r], CAP);
        if (t < deg) {
            int s = colF[(ibase + r) * CAP + t];
            su.l0.sptr[r][t] = (s < Uc) ? ue + (size_t)uid[s] * Dc
                                        : pe + (size_t)pid[s - Uc] * Dc;
            su.l0.snrm[r][t] = rsqrtf((float)(cnt[s] + 1));
        }
    }
    __syncthreads();
    {   // wave wv: node r = wv>>1, neighbor half h = wv&1
        int wv = t >> 6, ln = t & 63;
        int r = wv >> 1, h = wv & 1;
        int i = ibase + r;
        int dg = min(c[r], CAP);
        int dg2 = dg >> 1;
        int j0 = h ? dg2 : 0, j1 = h ? dg : dg2;
        float2 acc = make_float2(0.f, 0.f);
        if (h == 0) {
            const float* xi = (i < Uc) ? ue + (size_t)uid[i] * Dc
                                       : pe + (size_t)pid[i - Uc] * Dc;
            float2 a2 = *(const float2*)(xi + ln * 2);
            acc.x = di[r] * a2.x;
            acc.y = di[r] * a2.y;
        }
        int j = j0;
        for (; j + 8 <= j1; j += 8) {
            float n0 = su.l0.snrm[r][j],     n1 = su.l0.snrm[r][j + 1];
            float n2 = su.l0.snrm[r][j + 2], n3 = su.l0.snrm[r][j + 3];
            float n4 = su.l0.snrm[r][j + 4], n5 = su.l0.snrm[r][j + 5];
            float n6 = su.l0.snrm[r][j + 6], n7 = su.l0.snrm[r][j + 7];
            float2 r0 = *(const float2*)(su.l0.sptr[r][j]     + ln * 2);
            float2 r1 = *(const float2*)(su.l0.sptr[r][j + 1] + ln * 2);
            float2 r2 = *(const float2*)(su.l0.sptr[r][j + 2] + ln * 2);
            float2 r3 = *(const float2*)(su.l0.sptr[r][j + 3] + ln * 2);
            float2 r4 = *(const float2*)(su.l0.sptr[r][j + 4] + ln * 2);
            float2 r5 = *(const float2*)(su.l0.sptr[r][j + 5] + ln * 2);
            float2 r6 = *(const float2*)(su.l0.sptr[r][j + 6] + ln * 2);
            float2 r7 = *(const float2*)(su.l0.sptr[r][j + 7] + ln * 2);
            acc.x += n0 * r0.x + n1 * r1.x + n2 * r2.x + n3 * r3.x;
            acc.y += n0 * r0.y + n1 * r1.y + n2 * r2.y + n3 * r3.y;
            acc.x += n4 * r4.x + n5 * r5.x + n6 * r6.x + n7 * r7.x;
            acc.y += n4 * r4.y + n5 * r5.y + n6 * r6.y + n7 * r7.y;
        }
        for (; j + 4 <= j1; j += 4) {
            float n0 = su.l0.snrm[r][j],     n1 = su.l0.snrm[r][j + 1];
            float n2 = su.l0.snrm[r][j + 2], n3 = su.l0.snrm[r][j + 3];
            float2 r0 = *(const float2*)(su.l0.sptr[r][j]     + ln * 2);
            float2 r1 = *(const float2*)(su.l0.sptr[r][j + 1] + ln * 2);
            float2 r2 = *(const float2*)(su.l0.sptr[r][j + 2] + ln * 2);
            float2 r3 = *(const float2*)(su.l0.sptr[r][j + 3] + ln * 2);
            acc.x += n0 * r0.x + n1 * r1.x + n2 * r2.x + n3 * r3.x;
            acc.y += n0 * r0.y + n1 * r1.y + n2 * r2.y + n3 * r3.y;
        }
        for (; j < j1; j++) {
            float2 r0 = *(const float2*)(su.l0.sptr[r][j] + ln * 2);
            acc.x += su.l0.snrm[r][j] * r0.x;
            acc.y += su.l0.snrm[r][j] * r0.y;
        }
        su.l0.pagg[wv][ln * 2]     = acc.x;
        su.l0.pagg[wv][ln * 2 + 1] = acc.y;
    }
    __syncthreads();
    {   // combine halves: thread -> (node r = t>>7, feature f = t&127), packed [f][r]
        int r = t >> 7, f = t & 127;
        su.l0.aggT[f][r] = di[r] * (su.l0.pagg[2 * r][f] + su.l0.pagg[2 * r + 1][f]);
    }
    __syncthreads();
    {   // GEMV: wave-k-split, lane -> 4 cols, W0 as float4
        int wv = t >> 6, ln = t & 63;
        int k0 = wv * (Dc / 4);   // 32 k per wave
        float4 a0 = {0.f, 0.f, 0.f, 0.f}, a1 = {0.f, 0.f, 0.f, 0.f};
        const float* Wp_ = W0 + (size_t)k0 * Hc + ln * 4;
#pragma unroll 8
        for (int kk = 0; kk < Dc / 4; kk++) {
            float2 g = *(const float2*)&su.l0.aggT[k0 + kk][0];
            float4 w = *(const float4*)(Wp_ + (size_t)kk * Hc);
            a0.x += g.x * w.x; a0.y += g.x * w.y; a0.z += g.x * w.z; a0.w += g.x * w.w;
            a1.x += g.y * w.x; a1.y += g.y * w.y; a1.z += g.y * w.z; a1.w += g.y * w.w;
        }
        *(float4*)&su.l0.red[wv][0][ln * 4] = a0;
        *(float4*)&su.l0.red[wv][1][ln * 4] = a1;
    }
    __syncthreads();
    {
        float bb = b0[t];
        float s0 = (su.l0.red[0][0][t] + su.l0.red[1][0][t]) +
                   (su.l0.red[2][0][t] + su.l0.red[3][0][t]) + bb;
        float s1 = (su.l0.red[0][1][t] + su.l0.red[1][1][t]) +
                   (su.l0.red[2][1][t] + su.l0.red[3][1][t]) + bb;
        out[(size_t)(ibase + 0) * Hc + t] = fmaxf(s0, 0.f);
        out[(size_t)(ibase + 1) * Hc + t] = fmaxf(s1, 0.f);
    }
}

// Wave-pair H-dim aggregation for 2 nodes: wave wv -> (node wv>>1, half wv&1),
// lane l -> 4 features. Partials to pagg; caller combines.
__device__ __forceinline__ void agg_wave2(const float* __restrict__ X,
                                          const int (*sidx)[CAP], const float (*snrm)[CAP],
                                          const int* c, const float* di, int ibase,
                                          float (*pagg)[Hc], int t) {
    int wv = t >> 6, ln = t & 63;
    int r = wv >> 1, h = wv & 1;
    int dg = min(c[r], CAP);
    int dg2 = dg >> 1;
    int j0 = h ? dg2 : 0, j1 = h ? dg : dg2;
    float4 acc = make_float4(0.f, 0.f, 0.f, 0.f);
    if (h == 0) {
        acc = *(const float4*)&X[(size_t)(ibase + r) * Hc + ln * 4];
        acc.x *= di[r]; acc.y *= di[r]; acc.z *= di[r]; acc.w *= di[r];
    }
    int j = j0;
    for (; j + 8 <= j1; j += 8) {
        float n0 = snrm[r][j],     n1 = snrm[r][j + 1];
        float n2 = snrm[r][j + 2], n3 = snrm[r][j + 3];
        float n4 = snrm[r][j + 4], n5 = snrm[r][j + 5];
        float n6 = snrm[r][j + 6], n7 = snrm[r][j + 7];
        float4 r0 = *(const float4*)&X[sidx[r][j]     + ln * 4];
        float4 r1 = *(const float4*)&X[sidx[r][j + 1] + ln * 4];
        float4 r2 = *(const float4*)&X[sidx[r][j + 2] + ln * 4];
        float4 r3 = *(const float4*)&X[sidx[r][j + 3] + ln * 4];
        float4 r4 = *(const float4*)&X[sidx[r][j + 4] + ln * 4];
        float4 r5 = *(const float4*)&X[sidx[r][j + 5] + ln * 4];
        float4 r6 = *(const float4*)&X[sidx[r][j + 6] + ln * 4];
        float4 r7 = *(const float4*)&X[sidx[r][j + 7] + ln * 4];
        fma4(acc, n0, r0); fma4(acc, n1, r1); fma4(acc, n2, r2); fma4(acc, n3, r3);
        fma4(acc, n4, r4); fma4(acc, n5, r5); fma4(acc, n6, r6); fma4(acc, n7, r7);
    }
    for (; j + 4 <= j1; j += 4) {
        float n0 = snrm[r][j],     n1 = snrm[r][j + 1];
        float n2 = snrm[r][j + 2], n3 = snrm[r][j + 3];
        float4 r0 = *(const float4*)&X[sidx[r][j]     + ln * 4];
        float4 r1 = *(const float4*)&X[sidx[r][j + 1] + ln * 4];
        float4 r2 = *(const float4*)&X[sidx[r][j + 2] + ln * 4];
        float4 r3 = *(const float4*)&X[sidx[r][j + 3] + ln * 4];
        fma4(acc, n0, r0); fma4(acc, n1, r1); fma4(acc, n2, r2); fma4(acc, n3, r3);
    }
    for (; j < j1; j++) {
        float4 r0 = *(const float4*)&X[sidx[r][j] + ln * 4];
        fma4(acc, snrm[r][j], r0);
    }
    *(float4*)&pagg[wv][ln * 4] = acc;
}

// GEMV helper: wave-k-split over Hc rows of W, lane -> 4 cols, inputs packed
// in aggT[k][2], partials to red[wv][node][col].
__device__ __forceinline__ void gemv_wsplit(const float (*aggT)[2],
                                            const float* __restrict__ W,
                                            float (*red)[2][Hc], int t) {
    int wv = t >> 6, ln = t & 63;
    int k0 = wv * (Hc / 4);   // 64 k per wave
    float4 a0 = {0.f, 0.f, 0.f, 0.f}, a1 = {0.f, 0.f, 0.f, 0.f};
    const float* Wp_ = W + (size_t)k0 * Hc + ln * 4;
#pragma unroll 8
    for (int kk = 0; kk < Hc / 4; kk++) {
        float2 g = *(const float2*)&aggT[k0 + kk][0];
        float4 w = *(const float4*)(Wp_ + (size_t)kk * Hc);
        a0.x += g.x * w.x; a0.y += g.x * w.y; a0.z += g.x * w.z; a0.w += g.x * w.w;
        a1.x += g.y * w.x; a1.y += g.y * w.y; a1.z += g.y * w.z; a1.w += g.y * w.w;
    }
    *(float4*)&red[wv][0][ln * 4] = a0;
    *(float4*)&red[wv][1][ln * 4] = a1;
}

// Common head for hidden layers: build sidx/snrm, aggregate, pack aggT.
__device__ __forceinline__ void layer_head(SharedU& su, int b, int t,
        const float* __restrict__ X, const int* __restrict__ cnt,
        const int* __restrict__ colF, int* c, float* di) {
    int ibase = b * 2;
#pragma unroll
    for (int r = 0; r < 2; r++) {
        c[r] = cnt[ibase + r];
        di[r] = rsqrtf((float)(c[r] + 1));
        int deg = min(c[r], CAP);
        if (t < deg) {
            int s = colF[(ibase + r) * CAP + t];
            su.lh.sidx[r][t] = s * Hc;
            su.lh.snrm[r][t] = rsqrtf((float)(cnt[s] + 1));
        }
    }
    __syncthreads();
    agg_wave2(X, su.lh.sidx, su.lh.snrm, c, di, ibase, su.lh.pagg, t);
    __syncthreads();
    *(float2*)&su.lh.aggT[t][0] =
        make_float2(di[0] * (su.lh.pagg[0][t] + su.lh.pagg[1][t]),
                    di[1] * (su.lh.pagg[2][t] + su.lh.pagg[3][t]));
    __syncthreads();
}

// ---------------- middle layer phase: relu(agg(X) @ W + b) -> out --------------
__device__ void phase_lh(SharedU& su, int b, int t,
        const float* __restrict__ X, const float* __restrict__ W,
        const float* __restrict__ bias, const int* __restrict__ cnt,
        const int* __restrict__ colF, float* __restrict__ out) {
    int c[2]; float di[2];
    layer_head(su, b, t, X, cnt, colF, c, di);
    gemv_wsplit(su.lh.aggT, W, su.lh.red, t);
    __syncthreads();
    int ibase = b * 2;
    float bb = bias[t];
    float s0 = (su.lh.red[0][0][t] + su.lh.red[1][0][t]) +
               (su.lh.red[2][0][t] + su.lh.red[3][0][t]) + bb;
    float s1 = (su.lh.red[0][1][t] + su.lh.red[1][1][t]) +
               (su.lh.red[2][1][t] + su.lh.red[3][1][t]) + bb;
    out[(size_t)(ibase + 0) * Hc + t] = fmaxf(s0, 0.f);
    out[(size_t)(ibase + 1) * Hc + t] = fmaxf(s1, 0.f);
}

// ---------------- last layer + predictor-operand fusion phase ------------------
__device__ void phase_lht(SharedU& su, int b, int t,
        const float* __restrict__ X, const float* __restrict__ W2,
        const float* __restrict__ b2, const int* __restrict__ cnt,
        const int* __restrict__ colF,
        const float* __restrict__ Wup, const float* __restrict__ Wpp,
        const float* __restrict__ bvu, const float* __restrict__ bvp,
        float* __restrict__ AuT, float* __restrict__ ApT) {
    int c[2]; float di[2];
    layer_head(su, b, t, X, cnt, colF, c, di);
    // GEMV 1: x = relu(agg @ W2 + b2) -> xlocT
    gemv_wsplit(su.lh.aggT, W2, su.lh.red, t);
    __syncthreads();
    {
        float bb = b2[t];
        float s0 = (su.lh.red[0][0][t] + su.lh.red[1][0][t]) +
                   (su.lh.red[2][0][t] + su.lh.red[3][0][t]) + bb;
        float s1 = (su.lh.red[0][1][t] + su.lh.red[1][1][t]) +
                   (su.lh.red[2][1][t] + su.lh.red[3][1][t]) + bb;
        *(float2*)&su.lh.xlocT[t][0] = make_float2(fmaxf(s0, 0.f), fmaxf(s1, 0.f));
    }
    __syncthreads();
    // GEMV 2: AuT/ApT[t][rloc..rloc+2] = xloc @ Wsel[:,t] + bsel[t]
    gemv_wsplit(su.lh.xlocT, (b < 256) ? Wup : Wpp, su.lh.red, t);
    __syncthreads();
    {
        int ibase = b * 2;
        const float* bsel = (b < 256) ? bvu : bvp;
        float* YT  = (b < 256) ? AuT : ApT;
        int ldy    = (b < 256) ? Uc : Pc;
        int rloc   = (b < 256) ? ibase : ibase - Uc;
        float bb = bsel[t];
        float s0 = (su.lh.red[0][0][t] + su.lh.red[1][0][t]) +
                   (su.lh.red[2][0][t] + su.lh.red[3][0][t]) + bb;
        float s1 = (su.lh.red[0][1][t] + su.lh.red[1][1][t]) +
                   (su.lh.red[2][1][t] + su.lh.red[3][1][t]) + bb;
        *(float2*)&YT[(size_t)t * ldy + rloc] = make_float2(s0, s1);
    }
}

// ---------------- predictor phase ----------------
// Tile: 8 users x 128 papers, 512 blocks. Wave wv -> users 2wv..2wv+1 (LDS
// broadcast); lane -> 2 consecutive papers (float2 coalesced).
__device__ void phase_pred(float* auS, int b, int t,
        const float* __restrict__ AuT, const float* __restrict__ ApT,
        const float* __restrict__ Wq2, const float* __restrict__ bq2,
        float* __restrict__ out) {
    int ub = (b >> 3) * 8, pb = (b & 7) * 128;
#pragma unroll
    for (int i = t; i < Hc * 8; i += 256) {
        int k = i >> 3, u = i & 7;
        auS[i] = AuT[(size_t)k * Uc + ub + u];
    }
    __syncthreads();
    int wv = t >> 6, ln = t & 63;
    const float* app = ApT + pb + ln * 2;
    const float* aup = auS + wv * 2;
    float acc[2][2] = {};
#pragma unroll 4
    for (int k = 0; k < Hc; k++) {
        float w = Wq2[k];                                   // uniform -> s_load
        float2 a = *(const float2*)(aup + k * 8);           // LDS broadcast
        float2 p = *(const float2*)(app + (size_t)k * Pc);  // coalesced 512 B
        acc[0][0] += fmaxf(a.x + p.x, 0.f) * w;
        acc[0][1] += fmaxf(a.x + p.y, 0.f) * w;
        acc[1][0] += fmaxf(a.y + p.x, 0.f) * w;
        acc[1][1] += fmaxf(a.y + p.y, 0.f) * w;
    }
    float bq = bq2[0];
#pragma unroll
    for (int r = 0; r < 2; r++) {
        int u = ub + wv * 2 + r;
        float2 o;
        o.x = 1.f / (1.f + __expf(-(acc[r][0] + bq)));
        o.y = 1.f / (1.f + __expf(-(acc[r][1] + bq)));
        *(float2*)&out[(size_t)u * Pc + pb + ln * 2] = o;
    }
}

// ---------------- fused cooperative kernel ----------------
struct KArgs {
    const int *uid, *pid, *e_src, *e_dst;
    const float *ue, *pe;
    const float *W0, *b0, *W1, *b1, *W2, *b2;
    const float *Wu, *bu, *Wp, *bp, *Wq1, *bq1, *Wq2, *bq2;
    int *cnt, *colF;
    float *xA, *xB, *Wup, *Wpp, *bvu, *bvp, *AuT, *ApT, *pred;
};

__global__ void __launch_bounds__(256, 3) k_all(KArgs A) {
    cg::grid_group g = cg::this_grid();
    __shared__ SharedU su;
    int t = threadIdx.x, b = blockIdx.x;
    // P0: zero bucket counters
    {
        int i = b * 256 + t;
        if (i < Nc) A.cnt[i] = 0;
    }
    g.sync();
    // P1: scatter | weight collapse | bias
    phase_front(b, t, A.e_src, A.e_dst, A.cnt, A.colF, A.Wu, A.Wp, A.Wq1,
                A.bu, A.bp, A.bq1, A.Wup, A.Wpp, A.bvu, A.bvp);
    g.sync();
    // P2-P4: GCN layers
    phase_l0(su, b, t, A.uid, A.pid, A.ue, A.pe, A.W0, A.b0, A.cnt, A.colF, A.xA);
    g.sync();
    phase_lh(su, b, t, A.xA, A.W1, A.b1, A.cnt, A.colF, A.xB);
    g.sync();
    phase_lht(su, b, t, A.xB, A.W2, A.b2, A.cnt, A.colF,
              A.Wup, A.Wpp, A.bvu, A.bvp, A.AuT, A.ApT);
    g.sync();
    // P5: predictor (512 active blocks)
    if (b < 512) phase_pred(su.pr.auS, b, t, A.AuT, A.ApT, A.Wq2, A.bq2, A.pred);
}

// ---------------- standalone kernels (fallback path) ----------------
__global__ void k_front(const int* __restrict__ e_src, const int* __restrict__ e_dst,
                        int* __restrict__ cnt, int* __restrict__ colF,
                        const float* __restrict__ Wu, const float* __restrict__ Wp,
                        const float* __restrict__ Wq1, const float* __restrict__ bu,
                        const float* __restrict__ bp, const float* __restrict__ bq1,
                        float* __restrict__ Wup, float* __restrict__ Wpp,
                        float* __restrict__ bvu, float* __restrict__ bvp) {
    phase_front(blockIdx.x, threadIdx.x, e_src, e_dst, cnt, colF, Wu, Wp, Wq1,
                bu, bp, bq1, Wup, Wpp, bvu, bvp);
}

__global__ void __launch_bounds__(256) k_l0(
        const int* __restrict__ uid, const int* __restrict__ pid,
        const float* __restrict__ ue, const float* __restrict__ pe,
        const float* __restrict__ W0, const float* __restrict__ b0,
        const int* __restrict__ cnt, const int* __restrict__ colF,
        float* __restrict__ out) {
    __shared__ SharedU su;
    phase_l0(su, blockIdx.x, threadIdx.x, uid, pid, ue, pe, W0, b0, cnt, colF, out);
}

__global__ void __launch_bounds__(256) k_lh(
        const float* __restrict__ X, const float* __restrict__ W,
        const float* __restrict__ bias, const int* __restrict__ cnt,
        const int* __restrict__ colF, float* __restrict__ out) {
    __shared__ SharedU su;
    phase_lh(su, blockIdx.x, threadIdx.x, X, W, bias, cnt, colF, out);
}

__global__ void __launch_bounds__(256) k_lht(
        const float* __restrict__ X, const float* __restrict__ W2,
        const float* __restrict__ b2, const int* __restrict__ cnt,
        const int* __restrict__ colF,
        const float* __restrict__ Wup, const float* __restrict__ Wpp,
        const float* __restrict__ bvu, const float* __restrict__ bvp,
        float* __restrict__ AuT, float* __restrict__ ApT) {
    __shared__ SharedU su;
    phase_lht(su, blockIdx.x, threadIdx.x, X, W2, b2, cnt, colF,
              Wup, Wpp, bvu, bvp, AuT, ApT);
}

__global__ void __launch_bounds__(256) k_pred(
        const float* __restrict__ AuT, const float* __restrict__ ApT,
        const float* __restrict__ Wq2, const float* __restrict__ bq2,
        float* __restrict__ out) {
    __shared__ SharedU su;
    phase_pred(su.pr.auS, blockIdx.x, threadIdx.x, AuT, ApT, Wq2, bq2, out);
}

// ---------------- launcher ----------------
extern "C" void kernel_launch(void* const* d_in, const int* in_sizes, int n_in,
                              void* d_out, int out_size, void* d_ws, size_t ws_size,
                              hipStream_t stream) {
    KArgs A;
    A.uid = (const int*)d_in[0];
    A.pid = (const int*)d_in[1];
    const int* ei = (const int*)d_in[2];   // [2,E]: src = ei[0..E), dst = ei[E..2E)
    A.e_src = ei;
    A.e_dst = ei + Ec;
    A.ue  = (const float*)d_in[4];
    A.pe  = (const float*)d_in[5];
    A.W0  = (const float*)d_in[6];  A.b0  = (const float*)d_in[7];
    A.W1  = (const float*)d_in[8];  A.b1  = (const float*)d_in[9];
    A.W2  = (const float*)d_in[10]; A.b2  = (const float*)d_in[11];
    A.Wu  = (const float*)d_in[12]; A.bu  = (const float*)d_in[13];
    A.Wp  = (const float*)d_in[14]; A.bp  = (const float*)d_in[15];
    A.Wq1 = (const float*)d_in[16]; A.bq1 = (const float*)d_in[17];
    A.Wq2 = (const float*)d_in[18]; A.bq2 = (const float*)d_in[19];

    char* w = (char*)d_ws;
    auto alloc = [&](size_t bytes) { char* p = w; w += (bytes + 255) & ~size_t(255); return p; };
    A.cnt  = (int*)alloc(Nc * 4);
    A.colF = (int*)alloc((size_t)Nc * CAP * 4);
    A.xA   = (float*)alloc((size_t)Nc * Hc * 4);
    A.xB   = (float*)alloc((size_t)Nc * Hc * 4);
    A.Wup  = (float*)alloc((size_t)Hc * Hc * 4);
    A.Wpp  = (float*)alloc((size_t)Hc * Hc * 4);
    A.bvu  = (float*)alloc(Hc * 4);
    A.bvp  = (float*)alloc(Hc * 4);
    A.AuT  = (float*)alloc((size_t)Hc * Uc * 4);
    A.ApT  = (float*)alloc((size_t)Hc * Pc * 4);
    A.pred = (float*)d_out;

    // Preferred: single fused cooperative kernel (zero + front + 3 layers + pred).
    void* kargs[] = { (void*)&A };
    hipError_t err = hipLaunchCooperativeKernel((void*)k_all, dim3(768), dim3(256),
                                                kargs, 0, stream);
    if (err == hipSuccess) return;

    // Fallback: proven 6-dispatch path.
    hipMemsetAsync(A.cnt, 0, Nc * 4, stream);
    k_front<<<642, 256, 0, stream>>>(A.e_src, A.e_dst, A.cnt, A.colF, A.Wu, A.Wp,
                                     A.Wq1, A.bu, A.bp, A.bq1, A.Wup, A.Wpp,
                                     A.bvu, A.bvp);
    k_l0<<<Nc / 2, 256, 0, stream>>>(A.uid, A.pid, A.ue, A.pe, A.W0, A.b0,
                                     A.cnt, A.colF, A.xA);
    k_lh<<<Nc / 2, 256, 0, stream>>>(A.xA, A.W1, A.b1, A.cnt, A.colF, A.xB);
    k_lht<<<Nc / 2, 256, 0, stream>>>(A.xB, A.W2, A.b2, A.cnt, A.colF,
                                      A.Wup, A.Wpp, A.bvu, A.bvp, A.AuT, A.ApT);
    k_pred<<<512, 256, 0, stream>>>(A.AuT, A.ApT, A.Wq2, A.bq2, A.pred);
}

// Round 4
// 613.547 us; speedup vs baseline: 1.1260x; 1.1260x over previous
//
#include <hip/hip_runtime.h>
#include <math.h>

// Problem constants
constexpr int Uc = 512;
constexpr int Pc = 1024;
constexpr int Dc = 128;
constexpr int Hc = 256;
constexpr int Ec = 98304;
constexpr int Nc = 1536;   // U + P
constexpr int CAP = 192;   // bucket capacity (deg ~ B(98304,1/1536): mu=64, sigma=8)
constexpr int GRID = 768;  // fused-kernel grid (3 blocks/CU on 256 CUs)

__device__ __forceinline__ void fma4(float4& a, float n, const float4 r) {
    a.x += n * r.x; a.y += n * r.y; a.z += n * r.z; a.w += n * r.w;
}

// Hand-rolled grid barrier (replaces cg::grid_group::sync, which measured
// ~110 us/sync in round 3). Release fence -> device-scope arrival -> relaxed
// agent-scope spin (s_sleep backoff) -> acquire fence. Each barrier uses its
// own counter (zeroed by the launcher's memset); timeout valve avoids hangs.
__device__ __forceinline__ void gbar(int* bar, int nblk) {
    __syncthreads();
    if (threadIdx.x == 0) {
        __threadfence();                       // release: L2 writeback (agent)
        atomicAdd(bar, 1);                     // device-scope by default
        int iters = 0;
        while (__hip_atomic_load(bar, __ATOMIC_RELAXED,
                                 __HIP_MEMORY_SCOPE_AGENT) < nblk) {
            __builtin_amdgcn_s_sleep(8);
            if (++iters > (1 << 22)) break;    // ~1 s safety valve -> visible fail
        }
        __threadfence();                       // acquire: L1/L2 invalidate
    }
    __syncthreads();
}

// Shared-memory union: one allocation reused across fused phases (19.5 KB).
union __align__(16) SharedU {
    struct {   // layer 0 (D=128)
        const float* sptr[2][CAP];
        float snrm[2][CAP];
        float pagg[4][Dc];
        float aggT[Dc][2];
        float red[4][2][Hc];
    } l0;
    struct {   // hidden layers (H=256)
        int sidx[2][CAP];
        float snrm[2][CAP];
        float pagg[4][Hc];
        float aggT[Hc][2];
        float xlocT[Hc][2];
        float red[4][2][Hc];
    } lh;
    struct {   // predictor
        float auS[Hc * 8];
    } pr;
};

// ---------------- GEMM core: 16 rows x 32 cols / 256-thread block ----------------
template <int K>
__device__ __forceinline__ void gemm_core16(const float* __restrict__ xr,
                                            const float* __restrict__ wc, int M,
                                            float& acc0, float& acc1) {
#pragma unroll 4
    for (int k = 0; k < K; k += 4) {
        float4 a = *(const float4*)(xr + k);
        float2 b0 = *(const float2*)(wc + (size_t)k * M);
        float2 b1 = *(const float2*)(wc + (size_t)(k + 1) * M);
        float2 b2 = *(const float2*)(wc + (size_t)(k + 2) * M);
        float2 b3 = *(const float2*)(wc + (size_t)(k + 3) * M);
        acc0 += a.x * b0.x; acc1 += a.x * b0.y;
        acc0 += a.y * b1.x; acc1 += a.y * b1.y;
        acc0 += a.z * b2.x; acc1 += a.z * b2.y;
        acc0 += a.w * b3.x; acc1 += a.w * b3.y;
    }
}

// ---------------- front phase: scatter | weight collapse | bias ----------------
__device__ __forceinline__ void phase_front(
        int b, int t,
        const int* __restrict__ e_src, const int* __restrict__ e_dst,
        int* __restrict__ cnt, int* __restrict__ colF,
        const float* __restrict__ Wu, const float* __restrict__ Wp,
        const float* __restrict__ Wq1, const float* __restrict__ bu,
        const float* __restrict__ bp, const float* __restrict__ bq1,
        float* __restrict__ Wup, float* __restrict__ Wpp,
        float* __restrict__ bvu, float* __restrict__ bvp) {
    if (b < 384) {
        int e = b * 256 + t;
        int d = e_dst[e];
        int pos = atomicAdd(&cnt[d], 1);
        if (pos < CAP) colF[d * CAP + pos] = e_src[e];
    } else if (b < 640) {
        int id = b - 384;
        int z = id >> 7, tile = id & 127;
        int tx = t & 15, ty = t >> 4;
        const float* X = z ? Wp : Wu;
        const float* W = Wq1 + (z ? (size_t)Dc * Hc : 0);
        float* Y = z ? Wpp : Wup;
        int row = (tile >> 3) * 16 + ty, col = (tile & 7) * 32 + tx * 2;
        float a0 = 0.f, a1 = 0.f;
        gemm_core16<Dc>(X + (size_t)row * Dc, W + col, Hc, a0, a1);
        *(float2*)&Y[(size_t)row * Hc + col] = make_float2(a0, a1);
    } else if (b == 640) {
        float s = bq1[t];
#pragma unroll 8
        for (int d = 0; d < Dc; d++) s += bu[d] * Wq1[d * Hc + t];
        bvu[t] = s;
    } else if (b == 641) {
        float s = 0.f;
#pragma unroll 8
        for (int d = 0; d < Dc; d++) s += bp[d] * Wq1[(Dc + d) * Hc + t];
        bvp[t] = s;
    }
}

// ---------------- layer 0 phase: agg(embeddings) @ W0 + b0, relu -> xA ---------
// 2 nodes / block (768 blocks). Waves (2r, 2r+1) aggregate node r over neighbor
// halves; lane l -> features 2l..2l+2 (D=128). GEMV wave-k-split, float4 W.
__device__ void phase_l0(SharedU& su, int b, int t,
        const int* __restrict__ uid, const int* __restrict__ pid,
        const float* __restrict__ ue, const float* __restrict__ pe,
        const float* __restrict__ W0, const float* __restrict__ b0,
        const int* __restrict__ cnt, const int* __restrict__ colF,
        float* __restrict__ out) {
    int ibase = b * 2;
    int c[2]; float di[2];
#pragma unroll
    for (int r = 0; r < 2; r++) {
        c[r] = cnt[ibase + r];
        di[r] = rsqrtf((float)(c[r] + 1));
        int deg = min(c[r], CAP);
        if (t < deg) {
            int s = colF[(ibase + r) * CAP + t];
            su.l0.sptr[r][t] = (s < Uc) ? ue + (size_t)uid[s] * Dc
                                        : pe + (size_t)pid[s - Uc] * Dc;
            su.l0.snrm[r][t] = rsqrtf((float)(cnt[s] + 1));
        }
    }
    __syncthreads();
    {   // wave wv: node r = wv>>1, neighbor half h = wv&1
        int wv = t >> 6, ln = t & 63;
        int r = wv >> 1, h = wv & 1;
        int i = ibase + r;
        int dg = min(c[r], CAP);
        int dg2 = dg >> 1;
        int j0 = h ? dg2 : 0, j1 = h ? dg : dg2;
        float2 acc = make_float2(0.f, 0.f);
        if (h == 0) {
            const float* xi = (i < Uc) ? ue + (size_t)uid[i] * Dc
                                       : pe + (size_t)pid[i - Uc] * Dc;
            float2 a2 = *(const float2*)(xi + ln * 2);
            acc.x = di[r] * a2.x;
            acc.y = di[r] * a2.y;
        }
        int j = j0;
        for (; j + 8 <= j1; j += 8) {
            float n0 = su.l0.snrm[r][j],     n1 = su.l0.snrm[r][j + 1];
            float n2 = su.l0.snrm[r][j + 2], n3 = su.l0.snrm[r][j + 3];
            float n4 = su.l0.snrm[r][j + 4], n5 = su.l0.snrm[r][j + 5];
            float n6 = su.l0.snrm[r][j + 6], n7 = su.l0.snrm[r][j + 7];
            float2 r0 = *(const float2*)(su.l0.sptr[r][j]     + ln * 2);
            float2 r1 = *(const float2*)(su.l0.sptr[r][j + 1] + ln * 2);
            float2 r2 = *(const float2*)(su.l0.sptr[r][j + 2] + ln * 2);
            float2 r3 = *(const float2*)(su.l0.sptr[r][j + 3] + ln * 2);
            float2 r4 = *(const float2*)(su.l0.sptr[r][j + 4] + ln * 2);
            float2 r5 = *(const float2*)(su.l0.sptr[r][j + 5] + ln * 2);
            float2 r6 = *(const float2*)(su.l0.sptr[r][j + 6] + ln * 2);
            float2 r7 = *(const float2*)(su.l0.sptr[r][j + 7] + ln * 2);
            acc.x += n0 * r0.x + n1 * r1.x + n2 * r2.x + n3 * r3.x;
            acc.y += n0 * r0.y + n1 * r1.y + n2 * r2.y + n3 * r3.y;
            acc.x += n4 * r4.x + n5 * r5.x + n6 * r6.x + n7 * r7.x;
            acc.y += n4 * r4.y + n5 * r5.y + n6 * r6.y + n7 * r7.y;
        }
        for (; j + 4 <= j1; j += 4) {
            float n0 = su.l0.snrm[r][j],     n1 = su.l0.snrm[r][j + 1];
            float n2 = su.l0.snrm[r][j + 2], n3 = su.l0.snrm[r][j + 3];
            float2 r0 = *(const float2*)(su.l0.sptr[r][j]     + ln * 2);
            float2 r1 = *(const float2*)(su.l0.sptr[r][j + 1] + ln * 2);
            float2 r2 = *(const float2*)(su.l0.sptr[r][j + 2] + ln * 2);
            float2 r3 = *(const float2*)(su.l0.sptr[r][j + 3] + ln * 2);
            acc.x += n0 * r0.x + n1 * r1.x + n2 * r2.x + n3 * r3.x;
            acc.y += n0 * r0.y + n1 * r1.y + n2 * r2.y + n3 * r3.y;
        }
        for (; j < j1; j++) {
            float2 r0 = *(const float2*)(su.l0.sptr[r][j] + ln * 2);
            acc.x += su.l0.snrm[r][j] * r0.x;
            acc.y += su.l0.snrm[r][j] * r0.y;
        }
        su.l0.pagg[wv][ln * 2]     = acc.x;
        su.l0.pagg[wv][ln * 2 + 1] = acc.y;
    }
    __syncthreads();
    {   // combine halves: thread -> (node r = t>>7, feature f = t&127), packed [f][r]
        int r = t >> 7, f = t & 127;
        su.l0.aggT[f][r] = di[r] * (su.l0.pagg[2 * r][f] + su.l0.pagg[2 * r + 1][f]);
    }
    __syncthreads();
    {   // GEMV: wave-k-split, lane -> 4 cols, W0 as float4
        int wv = t >> 6, ln = t & 63;
        int k0 = wv * (Dc / 4);   // 32 k per wave
        float4 a0 = {0.f, 0.f, 0.f, 0.f}, a1 = {0.f, 0.f, 0.f, 0.f};
        const float* Wp_ = W0 + (size_t)k0 * Hc + ln * 4;
#pragma unroll 8
        for (int kk = 0; kk < Dc / 4; kk++) {
            float2 g = *(const float2*)&su.l0.aggT[k0 + kk][0];
            float4 w = *(const float4*)(Wp_ + (size_t)kk * Hc);
            a0.x += g.x * w.x; a0.y += g.x * w.y; a0.z += g.x * w.z; a0.w += g.x * w.w;
            a1.x += g.y * w.x; a1.y += g.y * w.y; a1.z += g.y * w.z; a1.w += g.y * w.w;
        }
        *(float4*)&su.l0.red[wv][0][ln * 4] = a0;
        *(float4*)&su.l0.red[wv][1][ln * 4] = a1;
    }
    __syncthreads();
    {
        float bb = b0[t];
        float s0 = (su.l0.red[0][0][t] + su.l0.red[1][0][t]) +
                   (su.l0.red[2][0][t] + su.l0.red[3][0][t]) + bb;
        float s1 = (su.l0.red[0][1][t] + su.l0.red[1][1][t]) +
                   (su.l0.red[2][1][t] + su.l0.red[3][1][t]) + bb;
        out[(size_t)(ibase + 0) * Hc + t] = fmaxf(s0, 0.f);
        out[(size_t)(ibase + 1) * Hc + t] = fmaxf(s1, 0.f);
    }
}

// Wave-pair H-dim aggregation for 2 nodes: wave wv -> (node wv>>1, half wv&1),
// lane l -> 4 features. Partials to pagg; caller combines.
__device__ __forceinline__ void agg_wave2(const float* __restrict__ X,
                                          const int (*sidx)[CAP], const float (*snrm)[CAP],
                                          const int* c, const float* di, int ibase,
                                          float (*pagg)[Hc], int t) {
    int wv = t >> 6, ln = t & 63;
    int r = wv >> 1, h = wv & 1;
    int dg = min(c[r], CAP);
    int dg2 = dg >> 1;
    int j0 = h ? dg2 : 0, j1 = h ? dg : dg2;
    float4 acc = make_float4(0.f, 0.f, 0.f, 0.f);
    if (h == 0) {
        acc = *(const float4*)&X[(size_t)(ibase + r) * Hc + ln * 4];
        acc.x *= di[r]; acc.y *= di[r]; acc.z *= di[r]; acc.w *= di[r];
    }
    int j = j0;
    for (; j + 8 <= j1; j += 8) {
        float n0 = snrm[r][j],     n1 = snrm[r][j + 1];
        float n2 = snrm[r][j + 2], n3 = snrm[r][j + 3];
        float n4 = snrm[r][j + 4], n5 = snrm[r][j + 5];
        float n6 = snrm[r][j + 6], n7 = snrm[r][j + 7];
        float4 r0 = *(const float4*)&X[sidx[r][j]     + ln * 4];
        float4 r1 = *(const float4*)&X[sidx[r][j + 1] + ln * 4];
        float4 r2 = *(const float4*)&X[sidx[r][j + 2] + ln * 4];
        float4 r3 = *(const float4*)&X[sidx[r][j + 3] + ln * 4];
        float4 r4 = *(const float4*)&X[sidx[r][j + 4] + ln * 4];
        float4 r5 = *(const float4*)&X[sidx[r][j + 5] + ln * 4];
        float4 r6 = *(const float4*)&X[sidx[r][j + 6] + ln * 4];
        float4 r7 = *(const float4*)&X[sidx[r][j + 7] + ln * 4];
        fma4(acc, n0, r0); fma4(acc, n1, r1); fma4(acc, n2, r2); fma4(acc, n3, r3);
        fma4(acc, n4, r4); fma4(acc, n5, r5); fma4(acc, n6, r6); fma4(acc, n7, r7);
    }
    for (; j + 4 <= j1; j += 4) {
        float n0 = snrm[r][j],     n1 = snrm[r][j + 1];
        float n2 = snrm[r][j + 2], n3 = snrm[r][j + 3];
        float4 r0 = *(const float4*)&X[sidx[r][j]     + ln * 4];
        float4 r1 = *(const float4*)&X[sidx[r][j + 1] + ln * 4];
        float4 r2 = *(const float4*)&X[sidx[r][j + 2] + ln * 4];
        float4 r3 = *(const float4*)&X[sidx[r][j + 3] + ln * 4];
        fma4(acc, n0, r0); fma4(acc, n1, r1); fma4(acc, n2, r2); fma4(acc, n3, r3);
    }
    for (; j < j1; j++) {
        float4 r0 = *(const float4*)&X[sidx[r][j] + ln * 4];
        fma4(acc, snrm[r][j], r0);
    }
    *(float4*)&pagg[wv][ln * 4] = acc;
}

// GEMV helper: wave-k-split over Hc rows of W, lane -> 4 cols, inputs packed
// in aggT[k][2], partials to red[wv][node][col].
__device__ __forceinline__ void gemv_wsplit(const float (*aggT)[2],
                                            const float* __restrict__ W,
                                            float (*red)[2][Hc], int t) {
    int wv = t >> 6, ln = t & 63;
    int k0 = wv * (Hc / 4);   // 64 k per wave
    float4 a0 = {0.f, 0.f, 0.f, 0.f}, a1 = {0.f, 0.f, 0.f, 0.f};
    const float* Wp_ = W + (size_t)k0 * Hc + ln * 4;
#pragma unroll 8
    for (int kk = 0; kk < Hc / 4; kk++) {
        float2 g = *(const float2*)&aggT[k0 + kk][0];
        float4 w = *(const float4*)(Wp_ + (size_t)kk * Hc);
        a0.x += g.x * w.x; a0.y += g.x * w.y; a0.z += g.x * w.z; a0.w += g.x * w.w;
        a1.x += g.y * w.x; a1.y += g.y * w.y; a1.z += g.y * w.z; a1.w += g.y * w.w;
    }
    *(float4*)&red[wv][0][ln * 4] = a0;
    *(float4*)&red[wv][1][ln * 4] = a1;
}

// Common head for hidden layers: build sidx/snrm, aggregate, pack aggT.
__device__ __forceinline__ void layer_head(SharedU& su, int b, int t,
        const float* __restrict__ X, const int* __restrict__ cnt,
        const int* __restrict__ colF, int* c, float* di) {
    int ibase = b * 2;
#pragma unroll
    for (int r = 0; r < 2; r++) {
        c[r] = cnt[ibase + r];
        di[r] = rsqrtf((float)(c[r] + 1));
        int deg = min(c[r], CAP);
        if (t < deg) {
            int s = colF[(ibase + r) * CAP + t];
            su.lh.sidx[r][t] = s * Hc;
            su.lh.snrm[r][t] = rsqrtf((float)(cnt[s] + 1));
        }
    }
    __syncthreads();
    agg_wave2(X, su.lh.sidx, su.lh.snrm, c, di, ibase, su.lh.pagg, t);
    __syncthreads();
    *(float2*)&su.lh.aggT[t][0] =
        make_float2(di[0] * (su.lh.pagg[0][t] + su.lh.pagg[1][t]),
                    di[1] * (su.lh.pagg[2][t] + su.lh.pagg[3][t]));
    __syncthreads();
}

// ---------------- middle layer phase: relu(agg(X) @ W + b) -> out --------------
__device__ void phase_lh(SharedU& su, int b, int t,
        const float* __restrict__ X, const float* __restrict__ W,
        const float* __restrict__ bias, const int* __restrict__ cnt,
        const int* __restrict__ colF, float* __restrict__ out) {
    int c[2]; float di[2];
    layer_head(su, b, t, X, cnt, colF, c, di);
    gemv_wsplit(su.lh.aggT, W, su.lh.red, t);
    __syncthreads();
    int ibase = b * 2;
    float bb = bias[t];
    float s0 = (su.lh.red[0][0][t] + su.lh.red[1][0][t]) +
               (su.lh.red[2][0][t] + su.lh.red[3][0][t]) + bb;
    float s1 = (su.lh.red[0][1][t] + su.lh.red[1][1][t]) +
               (su.lh.red[2][1][t] + su.lh.red[3][1][t]) + bb;
    out[(size_t)(ibase + 0) * Hc + t] = fmaxf(s0, 0.f);
    out[(size_t)(ibase + 1) * Hc + t] = fmaxf(s1, 0.f);
}

// ---------------- last layer + predictor-operand fusion phase ------------------
__device__ void phase_lht(SharedU& su, int b, int t,
        const float* __restrict__ X, const float* __restrict__ W2,
        const float* __restrict__ b2, const int* __restrict__ cnt,
        const int* __restrict__ colF,
        const float* __restrict__ Wup, const float* __restrict__ Wpp,
        const float* __restrict__ bvu, const float* __restrict__ bvp,
        float* __restrict__ AuT, float* __restrict__ ApT) {
    int c[2]; float di[2];
    layer_head(su, b, t, X, cnt, colF, c, di);
    // GEMV 1: x = relu(agg @ W2 + b2) -> xlocT
    gemv_wsplit(su.lh.aggT, W2, su.lh.red, t);
    __syncthreads();
    {
        float bb = b2[t];
        float s0 = (su.lh.red[0][0][t] + su.lh.red[1][0][t]) +
                   (su.lh.red[2][0][t] + su.lh.red[3][0][t]) + bb;
        float s1 = (su.lh.red[0][1][t] + su.lh.red[1][1][t]) +
                   (su.lh.red[2][1][t] + su.lh.red[3][1][t]) + bb;
        *(float2*)&su.lh.xlocT[t][0] = make_float2(fmaxf(s0, 0.f), fmaxf(s1, 0.f));
    }
    __syncthreads();
    // GEMV 2: AuT/ApT[t][rloc..rloc+2] = xloc @ Wsel[:,t] + bsel[t]
    gemv_wsplit(su.lh.xlocT, (b < 256) ? Wup : Wpp, su.lh.red, t);
    __syncthreads();
    {
        int ibase = b * 2;
        const float* bsel = (b < 256) ? bvu : bvp;
        float* YT  = (b < 256) ? AuT : ApT;
        int ldy    = (b < 256) ? Uc : Pc;
        int rloc   = (b < 256) ? ibase : ibase - Uc;
        float bb = bsel[t];
        float s0 = (su.lh.red[0][0][t] + su.lh.red[1][0][t]) +
                   (su.lh.red[2][0][t] + su.lh.red[3][0][t]) + bb;
        float s1 = (su.lh.red[0][1][t] + su.lh.red[1][1][t]) +
                   (su.lh.red[2][1][t] + su.lh.red[3][1][t]) + bb;
        *(float2*)&YT[(size_t)t * ldy + rloc] = make_float2(s0, s1);
    }
}

// ---------------- predictor phase ----------------
// Tile: 8 users x 128 papers, 512 blocks. Wave wv -> users 2wv..2wv+1 (LDS
// broadcast); lane -> 2 consecutive papers (float2 coalesced).
__device__ void phase_pred(float* auS, int b, int t,
        const float* __restrict__ AuT, const float* __restrict__ ApT,
        const float* __restrict__ Wq2, const float* __restrict__ bq2,
        float* __restrict__ out) {
    int ub = (b >> 3) * 8, pb = (b & 7) * 128;
#pragma unroll
    for (int i = t; i < Hc * 8; i += 256) {
        int k = i >> 3, u = i & 7;
        auS[i] = AuT[(size_t)k * Uc + ub + u];
    }
    __syncthreads();
    int wv = t >> 6, ln = t & 63;
    const float* app = ApT + pb + ln * 2;
    const float* aup = auS + wv * 2;
    float acc[2][2] = {};
#pragma unroll 4
    for (int k = 0; k < Hc; k++) {
        float w = Wq2[k];                                   // uniform -> s_load
        float2 a = *(const float2*)(aup + k * 8);           // LDS broadcast
        float2 p = *(const float2*)(app + (size_t)k * Pc);  // coalesced 512 B
        acc[0][0] += fmaxf(a.x + p.x, 0.f) * w;
        acc[0][1] += fmaxf(a.x + p.y, 0.f) * w;
        acc[1][0] += fmaxf(a.y + p.x, 0.f) * w;
        acc[1][1] += fmaxf(a.y + p.y, 0.f) * w;
    }
    float bq = bq2[0];
#pragma unroll
    for (int r = 0; r < 2; r++) {
        int u = ub + wv * 2 + r;
        float2 o;
        o.x = 1.f / (1.f + __expf(-(acc[r][0] + bq)));
        o.y = 1.f / (1.f + __expf(-(acc[r][1] + bq)));
        *(float2*)&out[(size_t)u * Pc + pb + ln * 2] = o;
    }
}

// ---------------- fused cooperative kernel ----------------
struct KArgs {
    const int *uid, *pid, *e_src, *e_dst;
    const float *ue, *pe;
    const float *W0, *b0, *W1, *b1, *W2, *b2;
    const float *Wu, *bu, *Wp, *bp, *Wq1, *bq1, *Wq2, *bq2;
    int *cnt, *colF, *bar;
    float *xA, *xB, *Wup, *Wpp, *bvu, *bvp, *AuT, *ApT, *pred;
};

__global__ void __launch_bounds__(256) k_all(KArgs A) {
    __shared__ SharedU su;
    int t = threadIdx.x, b = blockIdx.x;
    // P1: scatter | weight collapse | bias  (cnt zeroed by launcher memset)
    phase_front(b, t, A.e_src, A.e_dst, A.cnt, A.colF, A.Wu, A.Wp, A.Wq1,
                A.bu, A.bp, A.bq1, A.Wup, A.Wpp, A.bvu, A.bvp);
    gbar(A.bar + 0, GRID);
    // P2-P4: GCN layers
    phase_l0(su, b, t, A.uid, A.pid, A.ue, A.pe, A.W0, A.b0, A.cnt, A.colF, A.xA);
    gbar(A.bar + 1, GRID);
    phase_lh(su, b, t, A.xA, A.W1, A.b1, A.cnt, A.colF, A.xB);
    gbar(A.bar + 2, GRID);
    phase_lht(su, b, t, A.xB, A.W2, A.b2, A.cnt, A.colF,
              A.Wup, A.Wpp, A.bvu, A.bvp, A.AuT, A.ApT);
    gbar(A.bar + 3, GRID);
    // P5: predictor (512 active blocks)
    if (b < 512) phase_pred(su.pr.auS, b, t, A.AuT, A.ApT, A.Wq2, A.bq2, A.pred);
}

// ---------------- standalone kernels (fallback path) ----------------
__global__ void k_front(const int* __restrict__ e_src, const int* __restrict__ e_dst,
                        int* __restrict__ cnt, int* __restrict__ colF,
                        const float* __restrict__ Wu, const float* __restrict__ Wp,
                        const float* __restrict__ Wq1, const float* __restrict__ bu,
                        const float* __restrict__ bp, const float* __restrict__ bq1,
                        float* __restrict__ Wup, float* __restrict__ Wpp,
                        float* __restrict__ bvu, float* __restrict__ bvp) {
    phase_front(blockIdx.x, threadIdx.x, e_src, e_dst, cnt, colF, Wu, Wp, Wq1,
                bu, bp, bq1, Wup, Wpp, bvu, bvp);
}

__global__ void __launch_bounds__(256) k_l0(
        const int* __restrict__ uid, const int* __restrict__ pid,
        const float* __restrict__ ue, const float* __restrict__ pe,
        const float* __restrict__ W0, const float* __restrict__ b0,
        const int* __restrict__ cnt, const int* __restrict__ colF,
        float* __restrict__ out) {
    __shared__ SharedU su;
    phase_l0(su, blockIdx.x, threadIdx.x, uid, pid, ue, pe, W0, b0, cnt, colF, out);
}

__global__ void __launch_bounds__(256) k_lh(
        const float* __restrict__ X, const float* __restrict__ W,
        const float* __restrict__ bias, const int* __restrict__ cnt,
        const int* __restrict__ colF, float* __restrict__ out) {
    __shared__ SharedU su;
    phase_lh(su, blockIdx.x, threadIdx.x, X, W, bias, cnt, colF, out);
}

__global__ void __launch_bounds__(256) k_lht(
        const float* __restrict__ X, const float* __restrict__ W2,
        const float* __restrict__ b2, const int* __restrict__ cnt,
        const int* __restrict__ colF,
        const float* __restrict__ Wup, const float* __restrict__ Wpp,
        const float* __restrict__ bvu, const float* __restrict__ bvp,
        float* __restrict__ AuT, float* __restrict__ ApT) {
    __shared__ SharedU su;
    phase_lht(su, blockIdx.x, threadIdx.x, X, W2, b2, cnt, colF,
              Wup, Wpp, bvu, bvp, AuT, ApT);
}

__global__ void __launch_bounds__(256) k_pred(
        const float* __restrict__ AuT, const float* __restrict__ ApT,
        const float* __restrict__ Wq2, const float* __restrict__ bq2,
        float* __restrict__ out) {
    __shared__ SharedU su;
    phase_pred(su.pr.auS, blockIdx.x, threadIdx.x, AuT, ApT, Wq2, bq2, out);
}

// ---------------- launcher ----------------
extern "C" void kernel_launch(void* const* d_in, const int* in_sizes, int n_in,
                              void* d_out, int out_size, void* d_ws, size_t ws_size,
                              hipStream_t stream) {
    KArgs A;
    A.uid = (const int*)d_in[0];
    A.pid = (const int*)d_in[1];
    const int* ei = (const int*)d_in[2];   // [2,E]: src = ei[0..E), dst = ei[E..2E)
    A.e_src = ei;
    A.e_dst = ei + Ec;
    A.ue  = (const float*)d_in[4];
    A.pe  = (const float*)d_in[5];
    A.W0  = (const float*)d_in[6];  A.b0  = (const float*)d_in[7];
    A.W1  = (const float*)d_in[8];  A.b1  = (const float*)d_in[9];
    A.W2  = (const float*)d_in[10]; A.b2  = (const float*)d_in[11];
    A.Wu  = (const float*)d_in[12]; A.bu  = (const float*)d_in[13];
    A.Wp  = (const float*)d_in[14]; A.bp  = (const float*)d_in[15];
    A.Wq1 = (const float*)d_in[16]; A.bq1 = (const float*)d_in[17];
    A.Wq2 = (const float*)d_in[18]; A.bq2 = (const float*)d_in[19];

    char* w = (char*)d_ws;
    auto alloc = [&](size_t bytes) { char* p = w; w += (bytes + 255) & ~size_t(255); return p; };
    // cnt and barrier counters share one region so a single memset zeroes both.
    int* zreg = (int*)alloc(Nc * 4 + 64);
    A.cnt  = zreg;
    A.bar  = zreg + Nc;          // 16 ints (4 used)
    A.colF = (int*)alloc((size_t)Nc * CAP * 4);
    A.xA   = (float*)alloc((size_t)Nc * Hc * 4);
    A.xB   = (float*)alloc((size_t)Nc * Hc * 4);
    A.Wup  = (float*)alloc((size_t)Hc * Hc * 4);
    A.Wpp  = (float*)alloc((size_t)Hc * Hc * 4);
    A.bvu  = (float*)alloc(Hc * 4);
    A.bvp  = (float*)alloc(Hc * 4);
    A.AuT  = (float*)alloc((size_t)Hc * Uc * 4);
    A.ApT  = (float*)alloc((size_t)Hc * Pc * 4);
    A.pred = (float*)d_out;

    // 0: zero bucket + barrier counters (tiny DMA)
    hipMemsetAsync(A.cnt, 0, Nc * 4 + 64, stream);

    // Preferred: single fused cooperative kernel with hand-rolled barriers.
    void* kargs[] = { (void*)&A };
    hipError_t err = hipLaunchCooperativeKernel((void*)k_all, dim3(GRID), dim3(256),
                                                kargs, 0, stream);
    if (err == hipSuccess) return;

    // Fallback: proven 6-dispatch path.
    k_front<<<642, 256, 0, stream>>>(A.e_src, A.e_dst, A.cnt, A.colF, A.Wu, A.Wp,
                                     A.Wq1, A.bu, A.bp, A.bq1, A.Wup, A.Wpp,
                                     A.bvu, A.bvp);
    k_l0<<<Nc / 2, 256, 0, stream>>>(A.uid, A.pid, A.ue, A.pe, A.W0, A.b0,
                                     A.cnt, A.colF, A.xA);
    k_lh<<<Nc / 2, 256, 0, stream>>>(A.xA, A.W1, A.b1, A.cnt, A.colF, A.xB);
    k_lht<<<Nc / 2, 256, 0, stream>>>(A.xB, A.W2, A.b2, A.cnt, A.colF,
                                      A.Wup, A.Wpp, A.bvu, A.bvp, A.AuT, A.ApT);
    k_pred<<<512, 256, 0, stream>>>(A.AuT, A.ApT, A.Wq2, A.bq2, A.pred);
}

// Round 5
// 391.445 us; speedup vs baseline: 1.7648x; 1.5674x over previous
//
#include <hip/hip_runtime.h>
#include <math.h>

// Problem constants
constexpr int Uc = 512;
constexpr int Pc = 1024;
constexpr int Dc = 128;
constexpr int Hc = 256;
constexpr int Ec = 98304;
constexpr int Nc = 1536;   // U + P
constexpr int CAP = 192;   // bucket capacity (deg ~ B(98304,1/1536): mu=64, sigma=8)
constexpr int GRID = 768;  // fused-kernel grid (3 blocks/CU on 256 CUs)
constexpr int BAR_STRIDE = 1280;  // ints per barrier instance (64 leaves + 8 mids + root + go)

__device__ __forceinline__ void fma4(float4& a, float n, const float4 r) {
    a.x += n * r.x; a.y += n * r.y; a.z += n * r.z; a.w += n * r.w;
}

// Tree grid-barrier. Round-4's flat barrier measured ~115 us/sync: 768
// same-address device-scope RMWs serialize (~150 ns each) and 767 pollers
// congest the same line. Fix: 64 leaf counters (12 blocks each, 64 B apart)
// -> 8 mids -> root -> separate go flag; poll go with ~0.85 us backoff.
// Arrival serialization ~(12+8+8)x150ns ~ 4 us. Fences kept (correctness
// validated in round 4). Counters zeroed by launcher memset; timeout valve.
__device__ __forceinline__ void gbar2(int* bb, int b) {
    __syncthreads();
    if (threadIdx.x == 0) {
        __threadfence();                             // release: data -> coherence point
        int lc = atomicAdd(bb + (b & 63) * 16, 1);   // leaf: 12 blocks each
        if (lc == 11) {
            int mc = atomicAdd(bb + 1024 + ((b & 63) >> 3) * 16, 1);  // 8 leaves/mid
            if (mc == 7) {
                int rc = atomicAdd(bb + 1152, 1);    // 8 mids
                if (rc == 7)
                    __hip_atomic_store(bb + 1168, 1, __ATOMIC_RELAXED,
                                       __HIP_MEMORY_SCOPE_AGENT);
            }
        }
        int iters = 0;
        while (__hip_atomic_load(bb + 1168, __ATOMIC_RELAXED,
                                 __HIP_MEMORY_SCOPE_AGENT) == 0) {
            __builtin_amdgcn_s_sleep(32);            // ~2048 cyc backoff
            if (++iters > (1 << 20)) break;          // ~1 s safety valve
        }
        __threadfence();                             // acquire: drop stale L1/L2
    }
    __syncthreads();
}

// Shared-memory union: one allocation reused across fused phases (19.5 KB).
union __align__(16) SharedU {
    struct {   // layer 0 (D=128)
        const float* sptr[2][CAP];
        float snrm[2][CAP];
        float pagg[4][Dc];
        float aggT[Dc][2];
        float red[4][2][Hc];
    } l0;
    struct {   // hidden layers (H=256)
        int sidx[2][CAP];
        float snrm[2][CAP];
        float pagg[4][Hc];
        float aggT[Hc][2];
        float xlocT[Hc][2];
        float red[4][2][Hc];
    } lh;
    struct {   // predictor
        float auS[Hc * 8];
    } pr;
};

// ---------------- GEMM core: 16 rows x 32 cols / 256-thread block ----------------
template <int K>
__device__ __forceinline__ void gemm_core16(const float* __restrict__ xr,
                                            const float* __restrict__ wc, int M,
                                            float& acc0, float& acc1) {
#pragma unroll 4
    for (int k = 0; k < K; k += 4) {
        float4 a = *(const float4*)(xr + k);
        float2 b0 = *(const float2*)(wc + (size_t)k * M);
        float2 b1 = *(const float2*)(wc + (size_t)(k + 1) * M);
        float2 b2 = *(const float2*)(wc + (size_t)(k + 2) * M);
        float2 b3 = *(const float2*)(wc + (size_t)(k + 3) * M);
        acc0 += a.x * b0.x; acc1 += a.x * b0.y;
        acc0 += a.y * b1.x; acc1 += a.y * b1.y;
        acc0 += a.z * b2.x; acc1 += a.z * b2.y;
        acc0 += a.w * b3.x; acc1 += a.w * b3.y;
    }
}

// ---------------- front phase: scatter | weight collapse | bias ----------------
__device__ __forceinline__ void phase_front(
        int b, int t,
        const int* __restrict__ e_src, const int* __restrict__ e_dst,
        int* __restrict__ cnt, int* __restrict__ colF,
        const float* __restrict__ Wu, const float* __restrict__ Wp,
        const float* __restrict__ Wq1, const float* __restrict__ bu,
        const float* __restrict__ bp, const float* __restrict__ bq1,
        float* __restrict__ Wup, float* __restrict__ Wpp,
        float* __restrict__ bvu, float* __restrict__ bvp) {
    if (b < 384) {
        int e = b * 256 + t;
        int d = e_dst[e];
        int pos = atomicAdd(&cnt[d], 1);
        if (pos < CAP) colF[d * CAP + pos] = e_src[e];
    } else if (b < 640) {
        int id = b - 384;
        int z = id >> 7, tile = id & 127;
        int tx = t & 15, ty = t >> 4;
        const float* X = z ? Wp : Wu;
        const float* W = Wq1 + (z ? (size_t)Dc * Hc : 0);
        float* Y = z ? Wpp : Wup;
        int row = (tile >> 3) * 16 + ty, col = (tile & 7) * 32 + tx * 2;
        float a0 = 0.f, a1 = 0.f;
        gemm_core16<Dc>(X + (size_t)row * Dc, W + col, Hc, a0, a1);
        *(float2*)&Y[(size_t)row * Hc + col] = make_float2(a0, a1);
    } else if (b == 640) {
        float s = bq1[t];
#pragma unroll 8
        for (int d = 0; d < Dc; d++) s += bu[d] * Wq1[d * Hc + t];
        bvu[t] = s;
    } else if (b == 641) {
        float s = 0.f;
#pragma unroll 8
        for (int d = 0; d < Dc; d++) s += bp[d] * Wq1[(Dc + d) * Hc + t];
        bvp[t] = s;
    }
}

// ---------------- layer 0 phase: agg(embeddings) @ W0 + b0, relu -> xA ---------
// 2 nodes / block (768 blocks). Waves (2r, 2r+1) aggregate node r over neighbor
// halves; lane l -> features 2l..2l+2 (D=128). GEMV wave-k-split, float4 W.
__device__ void phase_l0(SharedU& su, int b, int t,
        const int* __restrict__ uid, const int* __restrict__ pid,
        const float* __restrict__ ue, const float* __restrict__ pe,
        const float* __restrict__ W0, const float* __restrict__ b0,
        const int* __restrict__ cnt, const int* __restrict__ colF,
        float* __restrict__ out) {
    int ibase = b * 2;
    int c[2]; float di[2];
#pragma unroll
    for (int r = 0; r < 2; r++) {
        c[r] = cnt[ibase + r];
        di[r] = rsqrtf((float)(c[r] + 1));
        int deg = min(c[r], CAP);
        if (t < deg) {
            int s = colF[(ibase + r) * CAP + t];
            su.l0.sptr[r][t] = (s < Uc) ? ue + (size_t)uid[s] * Dc
                                        : pe + (size_t)pid[s - Uc] * Dc;
            su.l0.snrm[r][t] = rsqrtf((float)(cnt[s] + 1));
        }
    }
    __syncthreads();
    {   // wave wv: node r = wv>>1, neighbor half h = wv&1
        int wv = t >> 6, ln = t & 63;
        int r = wv >> 1, h = wv & 1;
        int i = ibase + r;
        int dg = min(c[r], CAP);
        int dg2 = dg >> 1;
        int j0 = h ? dg2 : 0, j1 = h ? dg : dg2;
        float2 acc = make_float2(0.f, 0.f);
        if (h == 0) {
            const float* xi = (i < Uc) ? ue + (size_t)uid[i] * Dc
                                       : pe + (size_t)pid[i - Uc] * Dc;
            float2 a2 = *(const float2*)(xi + ln * 2);
            acc.x = di[r] * a2.x;
            acc.y = di[r] * a2.y;
        }
        int j = j0;
        for (; j + 8 <= j1; j += 8) {
            float n0 = su.l0.snrm[r][j],     n1 = su.l0.snrm[r][j + 1];
            float n2 = su.l0.snrm[r][j + 2], n3 = su.l0.snrm[r][j + 3];
            float n4 = su.l0.snrm[r][j + 4], n5 = su.l0.snrm[r][j + 5];
            float n6 = su.l0.snrm[r][j + 6], n7 = su.l0.snrm[r][j + 7];
            float2 r0 = *(const float2*)(su.l0.sptr[r][j]     + ln * 2);
            float2 r1 = *(const float2*)(su.l0.sptr[r][j + 1] + ln * 2);
            float2 r2 = *(const float2*)(su.l0.sptr[r][j + 2] + ln * 2);
            float2 r3 = *(const float2*)(su.l0.sptr[r][j + 3] + ln * 2);
            float2 r4 = *(const float2*)(su.l0.sptr[r][j + 4] + ln * 2);
            float2 r5 = *(const float2*)(su.l0.sptr[r][j + 5] + ln * 2);
            float2 r6 = *(const float2*)(su.l0.sptr[r][j + 6] + ln * 2);
            float2 r7 = *(const float2*)(su.l0.sptr[r][j + 7] + ln * 2);
            acc.x += n0 * r0.x + n1 * r1.x + n2 * r2.x + n3 * r3.x;
            acc.y += n0 * r0.y + n1 * r1.y + n2 * r2.y + n3 * r3.y;
            acc.x += n4 * r4.x + n5 * r5.x + n6 * r6.x + n7 * r7.x;
            acc.y += n4 * r4.y + n5 * r5.y + n6 * r6.y + n7 * r7.y;
        }
        for (; j + 4 <= j1; j += 4) {
            float n0 = su.l0.snrm[r][j],     n1 = su.l0.snrm[r][j + 1];
            float n2 = su.l0.snrm[r][j + 2], n3 = su.l0.snrm[r][j + 3];
            float2 r0 = *(const float2*)(su.l0.sptr[r][j]     + ln * 2);
            float2 r1 = *(const float2*)(su.l0.sptr[r][j + 1] + ln * 2);
            float2 r2 = *(const float2*)(su.l0.sptr[r][j + 2] + ln * 2);
            float2 r3 = *(const float2*)(su.l0.sptr[r][j + 3] + ln * 2);
            acc.x += n0 * r0.x + n1 * r1.x + n2 * r2.x + n3 * r3.x;
            acc.y += n0 * r0.y + n1 * r1.y + n2 * r2.y + n3 * r3.y;
        }
        for (; j < j1; j++) {
            float2 r0 = *(const float2*)(su.l0.sptr[r][j] + ln * 2);
            acc.x += su.l0.snrm[r][j] * r0.x;
            acc.y += su.l0.snrm[r][j] * r0.y;
        }
        su.l0.pagg[wv][ln * 2]     = acc.x;
        su.l0.pagg[wv][ln * 2 + 1] = acc.y;
    }
    __syncthreads();
    {   // combine halves: thread -> (node r = t>>7, feature f = t&127), packed [f][r]
        int r = t >> 7, f = t & 127;
        su.l0.aggT[f][r] = di[r] * (su.l0.pagg[2 * r][f] + su.l0.pagg[2 * r + 1][f]);
    }
    __syncthreads();
    {   // GEMV: wave-k-split, lane -> 4 cols, W0 as float4
        int wv = t >> 6, ln = t & 63;
        int k0 = wv * (Dc / 4);   // 32 k per wave
        float4 a0 = {0.f, 0.f, 0.f, 0.f}, a1 = {0.f, 0.f, 0.f, 0.f};
        const float* Wp_ = W0 + (size_t)k0 * Hc + ln * 4;
#pragma unroll 8
        for (int kk = 0; kk < Dc / 4; kk++) {
            float2 g = *(const float2*)&su.l0.aggT[k0 + kk][0];
            float4 w = *(const float4*)(Wp_ + (size_t)kk * Hc);
            a0.x += g.x * w.x; a0.y += g.x * w.y; a0.z += g.x * w.z; a0.w += g.x * w.w;
            a1.x += g.y * w.x; a1.y += g.y * w.y; a1.z += g.y * w.z; a1.w += g.y * w.w;
        }
        *(float4*)&su.l0.red[wv][0][ln * 4] = a0;
        *(float4*)&su.l0.red[wv][1][ln * 4] = a1;
    }
    __syncthreads();
    {
        float bb = b0[t];
        float s0 = (su.l0.red[0][0][t] + su.l0.red[1][0][t]) +
                   (su.l0.red[2][0][t] + su.l0.red[3][0][t]) + bb;
        float s1 = (su.l0.red[0][1][t] + su.l0.red[1][1][t]) +
                   (su.l0.red[2][1][t] + su.l0.red[3][1][t]) + bb;
        out[(size_t)(ibase + 0) * Hc + t] = fmaxf(s0, 0.f);
        out[(size_t)(ibase + 1) * Hc + t] = fmaxf(s1, 0.f);
    }
}

// Wave-pair H-dim aggregation for 2 nodes: wave wv -> (node wv>>1, half wv&1),
// lane l -> 4 features. Partials to pagg; caller combines.
__device__ __forceinline__ void agg_wave2(const float* __restrict__ X,
                                          const int (*sidx)[CAP], const float (*snrm)[CAP],
                                          const int* c, const float* di, int ibase,
                                          float (*pagg)[Hc], int t) {
    int wv = t >> 6, ln = t & 63;
    int r = wv >> 1, h = wv & 1;
    int dg = min(c[r], CAP);
    int dg2 = dg >> 1;
    int j0 = h ? dg2 : 0, j1 = h ? dg : dg2;
    float4 acc = make_float4(0.f, 0.f, 0.f, 0.f);
    if (h == 0) {
        acc = *(const float4*)&X[(size_t)(ibase + r) * Hc + ln * 4];
        acc.x *= di[r]; acc.y *= di[r]; acc.z *= di[r]; acc.w *= di[r];
    }
    int j = j0;
    for (; j + 8 <= j1; j += 8) {
        float n0 = snrm[r][j],     n1 = snrm[r][j + 1];
        float n2 = snrm[r][j + 2], n3 = snrm[r][j + 3];
        float n4 = snrm[r][j + 4], n5 = snrm[r][j + 5];
        float n6 = snrm[r][j + 6], n7 = snrm[r][j + 7];
        float4 r0 = *(const float4*)&X[sidx[r][j]     + ln * 4];
        float4 r1 = *(const float4*)&X[sidx[r][j + 1] + ln * 4];
        float4 r2 = *(const float4*)&X[sidx[r][j + 2] + ln * 4];
        float4 r3 = *(const float4*)&X[sidx[r][j + 3] + ln * 4];
        float4 r4 = *(const float4*)&X[sidx[r][j + 4] + ln * 4];
        float4 r5 = *(const float4*)&X[sidx[r][j + 5] + ln * 4];
        float4 r6 = *(const float4*)&X[sidx[r][j + 6] + ln * 4];
        float4 r7 = *(const float4*)&X[sidx[r][j + 7] + ln * 4];
        fma4(acc, n0, r0); fma4(acc, n1, r1); fma4(acc, n2, r2); fma4(acc, n3, r3);
        fma4(acc, n4, r4); fma4(acc, n5, r5); fma4(acc, n6, r6); fma4(acc, n7, r7);
    }
    for (; j + 4 <= j1; j += 4) {
        float n0 = snrm[r][j],     n1 = snrm[r][j + 1];
        float n2 = snrm[r][j + 2], n3 = snrm[r][j + 3];
        float4 r0 = *(const float4*)&X[sidx[r][j]     + ln * 4];
        float4 r1 = *(const float4*)&X[sidx[r][j + 1] + ln * 4];
        float4 r2 = *(const float4*)&X[sidx[r][j + 2] + ln * 4];
        float4 r3 = *(const float4*)&X[sidx[r][j + 3] + ln * 4];
        fma4(acc, n0, r0); fma4(acc, n1, r1); fma4(acc, n2, r2); fma4(acc, n3, r3);
    }
    for (; j < j1; j++) {
        float4 r0 = *(const float4*)&X[sidx[r][j] + ln * 4];
        fma4(acc, snrm[r][j], r0);
    }
    *(float4*)&pagg[wv][ln * 4] = acc;
}

// GEMV helper: wave-k-split over Hc rows of W, lane -> 4 cols, inputs packed
// in aggT[k][2], partials to red[wv][node][col].
__device__ __forceinline__ void gemv_wsplit(const float (*aggT)[2],
                                            const float* __restrict__ W,
                                            float (*red)[2][Hc], int t) {
    int wv = t >> 6, ln = t & 63;
    int k0 = wv * (Hc / 4);   // 64 k per wave
    float4 a0 = {0.f, 0.f, 0.f, 0.f}, a1 = {0.f, 0.f, 0.f, 0.f};
    const float* Wp_ = W + (size_t)k0 * Hc + ln * 4;
#pragma unroll 8
    for (int kk = 0; kk < Hc / 4; kk++) {
        float2 g = *(const float2*)&aggT[k0 + kk][0];
        float4 w = *(const float4*)(Wp_ + (size_t)kk * Hc);
        a0.x += g.x * w.x; a0.y += g.x * w.y; a0.z += g.x * w.z; a0.w += g.x * w.w;
        a1.x += g.y * w.x; a1.y += g.y * w.y; a1.z += g.y * w.z; a1.w += g.y * w.w;
    }
    *(float4*)&red[wv][0][ln * 4] = a0;
    *(float4*)&red[wv][1][ln * 4] = a1;
}

// Common head for hidden layers: build sidx/snrm, aggregate, pack aggT.
__device__ __forceinline__ void layer_head(SharedU& su, int b, int t,
        const float* __restrict__ X, const int* __restrict__ cnt,
        const int* __restrict__ colF, int* c, float* di) {
    int ibase = b * 2;
#pragma unroll
    for (int r = 0; r < 2; r++) {
        c[r] = cnt[ibase + r];
        di[r] = rsqrtf((float)(c[r] + 1));
        int deg = min(c[r], CAP);
        if (t < deg) {
            int s = colF[(ibase + r) * CAP + t];
            su.lh.sidx[r][t] = s * Hc;
            su.lh.snrm[r][t] = rsqrtf((float)(cnt[s] + 1));
        }
    }
    __syncthreads();
    agg_wave2(X, su.lh.sidx, su.lh.snrm, c, di, ibase, su.lh.pagg, t);
    __syncthreads();
    *(float2*)&su.lh.aggT[t][0] =
        make_float2(di[0] * (su.lh.pagg[0][t] + su.lh.pagg[1][t]),
                    di[1] * (su.lh.pagg[2][t] + su.lh.pagg[3][t]));
    __syncthreads();
}

// ---------------- middle layer phase: relu(agg(X) @ W + b) -> out --------------
__device__ void phase_lh(SharedU& su, int b, int t,
        const float* __restrict__ X, const float* __restrict__ W,
        const float* __restrict__ bias, const int* __restrict__ cnt,
        const int* __restrict__ colF, float* __restrict__ out) {
    int c[2]; float di[2];
    layer_head(su, b, t, X, cnt, colF, c, di);
    gemv_wsplit(su.lh.aggT, W, su.lh.red, t);
    __syncthreads();
    int ibase = b * 2;
    float bb = bias[t];
    float s0 = (su.lh.red[0][0][t] + su.lh.red[1][0][t]) +
               (su.lh.red[2][0][t] + su.lh.red[3][0][t]) + bb;
    float s1 = (su.lh.red[0][1][t] + su.lh.red[1][1][t]) +
               (su.lh.red[2][1][t] + su.lh.red[3][1][t]) + bb;
    out[(size_t)(ibase + 0) * Hc + t] = fmaxf(s0, 0.f);
    out[(size_t)(ibase + 1) * Hc + t] = fmaxf(s1, 0.f);
}

// ---------------- last layer + predictor-operand fusion phase ------------------
__device__ void phase_lht(SharedU& su, int b, int t,
        const float* __restrict__ X, const float* __restrict__ W2,
        const float* __restrict__ b2, const int* __restrict__ cnt,
        const int* __restrict__ colF,
        const float* __restrict__ Wup, const float* __restrict__ Wpp,
        const float* __restrict__ bvu, const float* __restrict__ bvp,
        float* __restrict__ AuT, float* __restrict__ ApT) {
    int c[2]; float di[2];
    layer_head(su, b, t, X, cnt, colF, c, di);
    // GEMV 1: x = relu(agg @ W2 + b2) -> xlocT
    gemv_wsplit(su.lh.aggT, W2, su.lh.red, t);
    __syncthreads();
    {
        float bb = b2[t];
        float s0 = (su.lh.red[0][0][t] + su.lh.red[1][0][t]) +
                   (su.lh.red[2][0][t] + su.lh.red[3][0][t]) + bb;
        float s1 = (su.lh.red[0][1][t] + su.lh.red[1][1][t]) +
                   (su.lh.red[2][1][t] + su.lh.red[3][1][t]) + bb;
        *(float2*)&su.lh.xlocT[t][0] = make_float2(fmaxf(s0, 0.f), fmaxf(s1, 0.f));
    }
    __syncthreads();
    // GEMV 2: AuT/ApT[t][rloc..rloc+2] = xloc @ Wsel[:,t] + bsel[t]
    gemv_wsplit(su.lh.xlocT, (b < 256) ? Wup : Wpp, su.lh.red, t);
    __syncthreads();
    {
        int ibase = b * 2;
        const float* bsel = (b < 256) ? bvu : bvp;
        float* YT  = (b < 256) ? AuT : ApT;
        int ldy    = (b < 256) ? Uc : Pc;
        int rloc   = (b < 256) ? ibase : ibase - Uc;
        float bb = bsel[t];
        float s0 = (su.lh.red[0][0][t] + su.lh.red[1][0][t]) +
                   (su.lh.red[2][0][t] + su.lh.red[3][0][t]) + bb;
        float s1 = (su.lh.red[0][1][t] + su.lh.red[1][1][t]) +
                   (su.lh.red[2][1][t] + su.lh.red[3][1][t]) + bb;
        *(float2*)&YT[(size_t)t * ldy + rloc] = make_float2(s0, s1);
    }
}

// ---------------- predictor phase ----------------
// Tile: 8 users x 128 papers, 512 blocks. Wave wv -> users 2wv..2wv+1 (LDS
// broadcast); lane -> 2 consecutive papers (float2 coalesced).
__device__ void phase_pred(float* auS, int b, int t,
        const float* __restrict__ AuT, const float* __restrict__ ApT,
        const float* __restrict__ Wq2, const float* __restrict__ bq2,
        float* __restrict__ out) {
    int ub = (b >> 3) * 8, pb = (b & 7) * 128;
#pragma unroll
    for (int i = t; i < Hc * 8; i += 256) {
        int k = i >> 3, u = i & 7;
        auS[i] = AuT[(size_t)k * Uc + ub + u];
    }
    __syncthreads();
    int wv = t >> 6, ln = t & 63;
    const float* app = ApT + pb + ln * 2;
    const float* aup = auS + wv * 2;
    float acc[2][2] = {};
#pragma unroll 4
    for (int k = 0; k < Hc; k++) {
        float w = Wq2[k];                                   // uniform -> s_load
        float2 a = *(const float2*)(aup + k * 8);           // LDS broadcast
        float2 p = *(const float2*)(app + (size_t)k * Pc);  // coalesced 512 B
        acc[0][0] += fmaxf(a.x + p.x, 0.f) * w;
        acc[0][1] += fmaxf(a.x + p.y, 0.f) * w;
        acc[1][0] += fmaxf(a.y + p.x, 0.f) * w;
        acc[1][1] += fmaxf(a.y + p.y, 0.f) * w;
    }
    float bq = bq2[0];
#pragma unroll
    for (int r = 0; r < 2; r++) {
        int u = ub + wv * 2 + r;
        float2 o;
        o.x = 1.f / (1.f + __expf(-(acc[r][0] + bq)));
        o.y = 1.f / (1.f + __expf(-(acc[r][1] + bq)));
        *(float2*)&out[(size_t)u * Pc + pb + ln * 2] = o;
    }
}

// ---------------- fused cooperative kernel ----------------
struct KArgs {
    const int *uid, *pid, *e_src, *e_dst;
    const float *ue, *pe;
    const float *W0, *b0, *W1, *b1, *W2, *b2;
    const float *Wu, *bu, *Wp, *bp, *Wq1, *bq1, *Wq2, *bq2;
    int *cnt, *colF, *bar;
    float *xA, *xB, *Wup, *Wpp, *bvu, *bvp, *AuT, *ApT, *pred;
};

__global__ void __launch_bounds__(256) k_all(KArgs A) {
    __shared__ SharedU su;
    int t = threadIdx.x, b = blockIdx.x;
    // P1: scatter | weight collapse | bias  (cnt zeroed by launcher memset)
    phase_front(b, t, A.e_src, A.e_dst, A.cnt, A.colF, A.Wu, A.Wp, A.Wq1,
                A.bu, A.bp, A.bq1, A.Wup, A.Wpp, A.bvu, A.bvp);
    gbar2(A.bar + 0 * BAR_STRIDE, b);
    // P2-P4: GCN layers
    phase_l0(su, b, t, A.uid, A.pid, A.ue, A.pe, A.W0, A.b0, A.cnt, A.colF, A.xA);
    gbar2(A.bar + 1 * BAR_STRIDE, b);
    phase_lh(su, b, t, A.xA, A.W1, A.b1, A.cnt, A.colF, A.xB);
    gbar2(A.bar + 2 * BAR_STRIDE, b);
    phase_lht(su, b, t, A.xB, A.W2, A.b2, A.cnt, A.colF,
              A.Wup, A.Wpp, A.bvu, A.bvp, A.AuT, A.ApT);
    gbar2(A.bar + 3 * BAR_STRIDE, b);
    // P5: predictor (512 active blocks)
    if (b < 512) phase_pred(su.pr.auS, b, t, A.AuT, A.ApT, A.Wq2, A.bq2, A.pred);
}

// ---------------- standalone kernels (fallback path) ----------------
__global__ void k_front(const int* __restrict__ e_src, const int* __restrict__ e_dst,
                        int* __restrict__ cnt, int* __restrict__ colF,
                        const float* __restrict__ Wu, const float* __restrict__ Wp,
                        const float* __restrict__ Wq1, const float* __restrict__ bu,
                        const float* __restrict__ bp, const float* __restrict__ bq1,
                        float* __restrict__ Wup, float* __restrict__ Wpp,
                        float* __restrict__ bvu, float* __restrict__ bvp) {
    phase_front(blockIdx.x, threadIdx.x, e_src, e_dst, cnt, colF, Wu, Wp, Wq1,
                bu, bp, bq1, Wup, Wpp, bvu, bvp);
}

__global__ void __launch_bounds__(256) k_l0(
        const int* __restrict__ uid, const int* __restrict__ pid,
        const float* __restrict__ ue, const float* __restrict__ pe,
        const float* __restrict__ W0, const float* __restrict__ b0,
        const int* __restrict__ cnt, const int* __restrict__ colF,
        float* __restrict__ out) {
    __shared__ SharedU su;
    phase_l0(su, blockIdx.x, threadIdx.x, uid, pid, ue, pe, W0, b0, cnt, colF, out);
}

__global__ void __launch_bounds__(256) k_lh(
        const float* __restrict__ X, const float* __restrict__ W,
        const float* __restrict__ bias, const int* __restrict__ cnt,
        const int* __restrict__ colF, float* __restrict__ out) {
    __shared__ SharedU su;
    phase_lh(su, blockIdx.x, threadIdx.x, X, W, bias, cnt, colF, out);
}

__global__ void __launch_bounds__(256) k_lht(
        const float* __restrict__ X, const float* __restrict__ W2,
        const float* __restrict__ b2, const int* __restrict__ cnt,
        const int* __restrict__ colF,
        const float* __restrict__ Wup, const float* __restrict__ Wpp,
        const float* __restrict__ bvu, const float* __restrict__ bvp,
        float* __restrict__ AuT, float* __restrict__ ApT) {
    __shared__ SharedU su;
    phase_lht(su, blockIdx.x, threadIdx.x, X, W2, b2, cnt, colF,
              Wup, Wpp, bvu, bvp, AuT, ApT);
}

__global__ void __launch_bounds__(256) k_pred(
        const float* __restrict__ AuT, const float* __restrict__ ApT,
        const float* __restrict__ Wq2, const float* __restrict__ bq2,
        float* __restrict__ out) {
    __shared__ SharedU su;
    phase_pred(su.pr.auS, blockIdx.x, threadIdx.x, AuT, ApT, Wq2, bq2, out);
}

// ---------------- launcher ----------------
extern "C" void kernel_launch(void* const* d_in, const int* in_sizes, int n_in,
                              void* d_out, int out_size, void* d_ws, size_t ws_size,
                              hipStream_t stream) {
    KArgs A;
    A.uid = (const int*)d_in[0];
    A.pid = (const int*)d_in[1];
    const int* ei = (const int*)d_in[2];   // [2,E]: src = ei[0..E), dst = ei[E..2E)
    A.e_src = ei;
    A.e_dst = ei + Ec;
    A.ue  = (const float*)d_in[4];
    A.pe  = (const float*)d_in[5];
    A.W0  = (const float*)d_in[6];  A.b0  = (const float*)d_in[7];
    A.W1  = (const float*)d_in[8];  A.b1  = (const float*)d_in[9];
    A.W2  = (const float*)d_in[10]; A.b2  = (const float*)d_in[11];
    A.Wu  = (const float*)d_in[12]; A.bu  = (const float*)d_in[13];
    A.Wp  = (const float*)d_in[14]; A.bp  = (const float*)d_in[15];
    A.Wq1 = (const float*)d_in[16]; A.bq1 = (const float*)d_in[17];
    A.Wq2 = (const float*)d_in[18]; A.bq2 = (const float*)d_in[19];

    char* w = (char*)d_ws;
    auto alloc = [&](size_t bytes) { char* p = w; w += (bytes + 255) & ~size_t(255); return p; };
    // cnt and barrier counters share one region so a single memset zeroes both.
    constexpr int BAR_BYTES = 4 * BAR_STRIDE * 4;   // 4 barrier instances
    int* zreg = (int*)alloc(Nc * 4 + BAR_BYTES);
    A.cnt  = zreg;
    A.bar  = zreg + Nc;
    A.colF = (int*)alloc((size_t)Nc * CAP * 4);
    A.xA   = (float*)alloc((size_t)Nc * Hc * 4);
    A.xB   = (float*)alloc((size_t)Nc * Hc * 4);
    A.Wup  = (float*)alloc((size_t)Hc * Hc * 4);
    A.Wpp  = (float*)alloc((size_t)Hc * Hc * 4);
    A.bvu  = (float*)alloc(Hc * 4);
    A.bvp  = (float*)alloc(Hc * 4);
    A.AuT  = (float*)alloc((size_t)Hc * Uc * 4);
    A.ApT  = (float*)alloc((size_t)Hc * Pc * 4);
    A.pred = (float*)d_out;

    // 0: zero bucket + barrier counters (tiny DMA)
    hipMemsetAsync(A.cnt, 0, Nc * 4 + BAR_BYTES, stream);

    // Preferred: single fused cooperative kernel with tree barriers.
    void* kargs[] = { (void*)&A };
    hipError_t err = hipLaunchCooperativeKernel((void*)k_all, dim3(GRID), dim3(256),
                                                kargs, 0, stream);
    if (err == hipSuccess) return;

    // Fallback: proven 6-dispatch path.
    k_front<<<642, 256, 0, stream>>>(A.e_src, A.e_dst, A.cnt, A.colF, A.Wu, A.Wp,
                                     A.Wq1, A.bu, A.bp, A.bq1, A.Wup, A.Wpp,
                                     A.bvu, A.bvp);
    k_l0<<<Nc / 2, 256, 0, stream>>>(A.uid, A.pid, A.ue, A.pe, A.W0, A.b0,
                                     A.cnt, A.colF, A.xA);
    k_lh<<<Nc / 2, 256, 0, stream>>>(A.xA, A.W1, A.b1, A.cnt, A.colF, A.xB);
    k_lht<<<Nc / 2, 256, 0, stream>>>(A.xB, A.W2, A.b2, A.cnt, A.colF,
                                      A.Wup, A.Wpp, A.bvu, A.bvp, A.AuT, A.ApT);
    k_pred<<<512, 256, 0, stream>>>(A.AuT, A.ApT, A.Wq2, A.bq2, A.pred);
}

// Round 6
// 256.218 us; speedup vs baseline: 2.6963x; 1.5278x over previous
//
#include <hip/hip_runtime.h>
#include <math.h>

// Problem constants
constexpr int Uc = 512;
constexpr int Pc = 1024;
constexpr int Dc = 128;
constexpr int Hc = 256;
constexpr int Ec = 98304;
constexpr int Nc = 1536;   // U + P
constexpr int CAP = 192;   // bucket capacity (deg ~ B(98304,1/1536): mu=64, sigma=8)
constexpr int GRID = 768;  // fused-kernel grid (3 blocks/CU on 256 CUs)
// Barrier instance layout (ints): 64 leaves*16 | 8 mids*16 | root | pad | 64 go*16
constexpr int BAR_STRIDE = 2304;

// ---- write-through agent-scope stores (land at IF; no fence needed later) ----
__device__ __forceinline__ void st_wt(float* p, float v) {
    __hip_atomic_store(p, v, __ATOMIC_RELAXED, __HIP_MEMORY_SCOPE_AGENT);
}
__device__ __forceinline__ void st_wt_i(int* p, int v) {
    __hip_atomic_store(p, v, __ATOMIC_RELAXED, __HIP_MEMORY_SCOPE_AGENT);
}
__device__ __forceinline__ void st_wt2(float* p, float2 v) {
    unsigned long long u;
    __builtin_memcpy(&u, &v, 8);
    __hip_atomic_store((unsigned long long*)p, u, __ATOMIC_RELAXED,
                       __HIP_MEMORY_SCOPE_AGENT);
}

// Fence-free tree grid-barrier. Round 4 (flat+fence): ~115 us/sync. Round 5
// (tree+fence): ~55 us/sync -> residual is the per-block __threadfence
// (768 redundant L2 wb/inv walks). This version has NO fences: cross-phase
// data is stored write-through (st_wt*), __syncthreads drains vmcnt(0) before
// arrival, and every cross-phase buffer is write-once-then-read (first read
// is post-barrier -> L2 miss -> fresh from IF). Arrival: 64 leaves -> 8 mids
// -> root; release: 64 per-leaf go flags (12 pollers each, s_sleep(8)).
__device__ __forceinline__ void gbar3(int* bb, int b) {
    __syncthreads();   // compiler emits s_waitcnt vmcnt(0) before s_barrier
    if (threadIdx.x == 0) {
        int leaf = b & 63;
        int lc = __hip_atomic_fetch_add(bb + leaf * 16, 1,
                                        __ATOMIC_RELAXED, __HIP_MEMORY_SCOPE_AGENT);
        if (lc == 11) {                          // last of 12 blocks on this leaf
            int mc = __hip_atomic_fetch_add(bb + 1024 + (leaf >> 3) * 16, 1,
                                            __ATOMIC_RELAXED, __HIP_MEMORY_SCOPE_AGENT);
            if (mc == 7) {                       // last of 8 leaves in this mid
                int rc = __hip_atomic_fetch_add(bb + 1152, 1,
                                                __ATOMIC_RELAXED, __HIP_MEMORY_SCOPE_AGENT);
                if (rc == 7) {                   // last mid -> broadcast go flags
#pragma unroll
                    for (int i = 0; i < 64; i++)
                        __hip_atomic_store(bb + 1216 + i * 16, 1, __ATOMIC_RELAXED,
                                           __HIP_MEMORY_SCOPE_AGENT);
                }
            }
        }
        int iters = 0;
        while (__hip_atomic_load(bb + 1216 + leaf * 16, __ATOMIC_RELAXED,
                                 __HIP_MEMORY_SCOPE_AGENT) == 0) {
            __builtin_amdgcn_s_sleep(8);         // ~512 cyc backoff, 12 pollers/line
            if (++iters > (1 << 22)) break;      // safety valve -> visible fail
        }
    }
    __syncthreads();
}

__device__ __forceinline__ void fma4(float4& a, float n, const float4 r) {
    a.x += n * r.x; a.y += n * r.y; a.z += n * r.z; a.w += n * r.w;
}

// Shared-memory union: one allocation reused across fused phases (19.5 KB).
union __align__(16) SharedU {
    struct {   // layer 0 (D=128)
        const float* sptr[2][CAP];
        float snrm[2][CAP];
        float pagg[4][Dc];
        float aggT[Dc][2];
        float red[4][2][Hc];
    } l0;
    struct {   // hidden layers (H=256)
        int sidx[2][CAP];
        float snrm[2][CAP];
        float pagg[4][Hc];
        float aggT[Hc][2];
        float xlocT[Hc][2];
        float red[4][2][Hc];
    } lh;
    struct {   // predictor
        float auS[Hc * 8];
    } pr;
};

// ---------------- GEMM core: 16 rows x 32 cols / 256-thread block ----------------
template <int K>
__device__ __forceinline__ void gemm_core16(const float* __restrict__ xr,
                                            const float* __restrict__ wc, int M,
                                            float& acc0, float& acc1) {
#pragma unroll 4
    for (int k = 0; k < K; k += 4) {
        float4 a = *(const float4*)(xr + k);
        float2 b0 = *(const float2*)(wc + (size_t)k * M);
        float2 b1 = *(const float2*)(wc + (size_t)(k + 1) * M);
        float2 b2 = *(const float2*)(wc + (size_t)(k + 2) * M);
        float2 b3 = *(const float2*)(wc + (size_t)(k + 3) * M);
        acc0 += a.x * b0.x; acc1 += a.x * b0.y;
        acc0 += a.y * b1.x; acc1 += a.y * b1.y;
        acc0 += a.z * b2.x; acc1 += a.z * b2.y;
        acc0 += a.w * b3.x; acc1 += a.w * b3.y;
    }
}

// ---------------- front phase: scatter | weight collapse | bias ----------------
__device__ __forceinline__ void phase_front(
        int b, int t,
        const int* __restrict__ e_src, const int* __restrict__ e_dst,
        int* __restrict__ cnt, int* __restrict__ colF,
        const float* __restrict__ Wu, const float* __restrict__ Wp,
        const float* __restrict__ Wq1, const float* __restrict__ bu,
        const float* __restrict__ bp, const float* __restrict__ bq1,
        float* __restrict__ Wup, float* __restrict__ Wpp,
        float* __restrict__ bvu, float* __restrict__ bvp) {
    if (b < 384) {
        int e = b * 256 + t;
        int d = e_dst[e];
        int pos = atomicAdd(&cnt[d], 1);
        if (pos < CAP) st_wt_i(&colF[d * CAP + pos], e_src[e]);
    } else if (b < 640) {
        int id = b - 384;
        int z = id >> 7, tile = id & 127;
        int tx = t & 15, ty = t >> 4;
        const float* X = z ? Wp : Wu;
        const float* W = Wq1 + (z ? (size_t)Dc * Hc : 0);
        float* Y = z ? Wpp : Wup;
        int row = (tile >> 3) * 16 + ty, col = (tile & 7) * 32 + tx * 2;
        float a0 = 0.f, a1 = 0.f;
        gemm_core16<Dc>(X + (size_t)row * Dc, W + col, Hc, a0, a1);
        st_wt2(&Y[(size_t)row * Hc + col], make_float2(a0, a1));
    } else if (b == 640) {
        float s = bq1[t];
#pragma unroll 8
        for (int d = 0; d < Dc; d++) s += bu[d] * Wq1[d * Hc + t];
        st_wt(&bvu[t], s);
    } else if (b == 641) {
        float s = 0.f;
#pragma unroll 8
        for (int d = 0; d < Dc; d++) s += bp[d] * Wq1[(Dc + d) * Hc + t];
        st_wt(&bvp[t], s);
    }
}

// ---------------- layer 0 phase: agg(embeddings) @ W0 + b0, relu -> xA ---------
// 2 nodes / block (768 blocks). Waves (2r, 2r+1) aggregate node r over neighbor
// halves; lane l -> features 2l..2l+2 (D=128). GEMV wave-k-split, float4 W.
__device__ void phase_l0(SharedU& su, int b, int t,
        const int* __restrict__ uid, const int* __restrict__ pid,
        const float* __restrict__ ue, const float* __restrict__ pe,
        const float* __restrict__ W0, const float* __restrict__ b0,
        const int* __restrict__ cnt, const int* __restrict__ colF,
        float* __restrict__ out) {
    int ibase = b * 2;
    int c[2]; float di[2];
#pragma unroll
    for (int r = 0; r < 2; r++) {
        c[r] = cnt[ibase + r];
        di[r] = rsqrtf((float)(c[r] + 1));
        int deg = min(c[r], CAP);
        if (t < deg) {
            int s = colF[(ibase + r) * CAP + t];
            su.l0.sptr[r][t] = (s < Uc) ? ue + (size_t)uid[s] * Dc
                                        : pe + (size_t)pid[s - Uc] * Dc;
            su.l0.snrm[r][t] = rsqrtf((float)(cnt[s] + 1));
        }
    }
    __syncthreads();
    {   // wave wv: node r = wv>>1, neighbor half h = wv&1
        int wv = t >> 6, ln = t & 63;
        int r = wv >> 1, h = wv & 1;
        int i = ibase + r;
        int dg = min(c[r], CAP);
        int dg2 = dg >> 1;
        int j0 = h ? dg2 : 0, j1 = h ? dg : dg2;
        float2 acc = make_float2(0.f, 0.f);
        if (h == 0) {
            const float* xi = (i < Uc) ? ue + (size_t)uid[i] * Dc
                                       : pe + (size_t)pid[i - Uc] * Dc;
            float2 a2 = *(const float2*)(xi + ln * 2);
            acc.x = di[r] * a2.x;
            acc.y = di[r] * a2.y;
        }
        int j = j0;
        for (; j + 8 <= j1; j += 8) {
            float n0 = su.l0.snrm[r][j],     n1 = su.l0.snrm[r][j + 1];
            float n2 = su.l0.snrm[r][j + 2], n3 = su.l0.snrm[r][j + 3];
            float n4 = su.l0.snrm[r][j + 4], n5 = su.l0.snrm[r][j + 5];
            float n6 = su.l0.snrm[r][j + 6], n7 = su.l0.snrm[r][j + 7];
            float2 r0 = *(const float2*)(su.l0.sptr[r][j]     + ln * 2);
            float2 r1 = *(const float2*)(su.l0.sptr[r][j + 1] + ln * 2);
            float2 r2 = *(const float2*)(su.l0.sptr[r][j + 2] + ln * 2);
            float2 r3 = *(const float2*)(su.l0.sptr[r][j + 3] + ln * 2);
            float2 r4 = *(const float2*)(su.l0.sptr[r][j + 4] + ln * 2);
            float2 r5 = *(const float2*)(su.l0.sptr[r][j + 5] + ln * 2);
            float2 r6 = *(const float2*)(su.l0.sptr[r][j + 6] + ln * 2);
            float2 r7 = *(const float2*)(su.l0.sptr[r][j + 7] + ln * 2);
            acc.x += n0 * r0.x + n1 * r1.x + n2 * r2.x + n3 * r3.x;
            acc.y += n0 * r0.y + n1 * r1.y + n2 * r2.y + n3 * r3.y;
            acc.x += n4 * r4.x + n5 * r5.x + n6 * r6.x + n7 * r7.x;
            acc.y += n4 * r4.y + n5 * r5.y + n6 * r6.y + n7 * r7.y;
        }
        for (; j + 4 <= j1; j += 4) {
            float n0 = su.l0.snrm[r][j],     n1 = su.l0.snrm[r][j + 1];
            float n2 = su.l0.snrm[r][j + 2], n3 = su.l0.snrm[r][j + 3];
            float2 r0 = *(const float2*)(su.l0.sptr[r][j]     + ln * 2);
            float2 r1 = *(const float2*)(su.l0.sptr[r][j + 1] + ln * 2);
            float2 r2 = *(const float2*)(su.l0.sptr[r][j + 2] + ln * 2);
            float2 r3 = *(const float2*)(su.l0.sptr[r][j + 3] + ln * 2);
            acc.x += n0 * r0.x + n1 * r1.x + n2 * r2.x + n3 * r3.x;
            acc.y += n0 * r0.y + n1 * r1.y + n2 * r2.y + n3 * r3.y;
        }
        for (; j < j1; j++) {
            float2 r0 = *(const float2*)(su.l0.sptr[r][j] + ln * 2);
            acc.x += su.l0.snrm[r][j] * r0.x;
            acc.y += su.l0.snrm[r][j] * r0.y;
        }
        su.l0.pagg[wv][ln * 2]     = acc.x;
        su.l0.pagg[wv][ln * 2 + 1] = acc.y;
    }
    __syncthreads();
    {   // combine halves: thread -> (node r = t>>7, feature f = t&127), packed [f][r]
        int r = t >> 7, f = t & 127;
        su.l0.aggT[f][r] = di[r] * (su.l0.pagg[2 * r][f] + su.l0.pagg[2 * r + 1][f]);
    }
    __syncthreads();
    {   // GEMV: wave-k-split, lane -> 4 cols, W0 as float4
        int wv = t >> 6, ln = t & 63;
        int k0 = wv * (Dc / 4);   // 32 k per wave
        float4 a0 = {0.f, 0.f, 0.f, 0.f}, a1 = {0.f, 0.f, 0.f, 0.f};
        const float* Wp_ = W0 + (size_t)k0 * Hc + ln * 4;
#pragma unroll 8
        for (int kk = 0; kk < Dc / 4; kk++) {
            float2 g = *(const float2*)&su.l0.aggT[k0 + kk][0];
            float4 w = *(const float4*)(Wp_ + (size_t)kk * Hc);
            a0.x += g.x * w.x; a0.y += g.x * w.y; a0.z += g.x * w.z; a0.w += g.x * w.w;
            a1.x += g.y * w.x; a1.y += g.y * w.y; a1.z += g.y * w.z; a1.w += g.y * w.w;
        }
        *(float4*)&su.l0.red[wv][0][ln * 4] = a0;
        *(float4*)&su.l0.red[wv][1][ln * 4] = a1;
    }
    __syncthreads();
    {
        float bb = b0[t];
        float s0 = (su.l0.red[0][0][t] + su.l0.red[1][0][t]) +
                   (su.l0.red[2][0][t] + su.l0.red[3][0][t]) + bb;
        float s1 = (su.l0.red[0][1][t] + su.l0.red[1][1][t]) +
                   (su.l0.red[2][1][t] + su.l0.red[3][1][t]) + bb;
        st_wt(&out[(size_t)(ibase + 0) * Hc + t], fmaxf(s0, 0.f));
        st_wt(&out[(size_t)(ibase + 1) * Hc + t], fmaxf(s1, 0.f));
    }
}

// Wave-pair H-dim aggregation for 2 nodes: wave wv -> (node wv>>1, half wv&1),
// lane l -> 4 features. Partials to pagg; caller combines.
__device__ __forceinline__ void agg_wave2(const float* __restrict__ X,
                                          const int (*sidx)[CAP], const float (*snrm)[CAP],
                                          const int* c, const float* di, int ibase,
                                          float (*pagg)[Hc], int t) {
    int wv = t >> 6, ln = t & 63;
    int r = wv >> 1, h = wv & 1;
    int dg = min(c[r], CAP);
    int dg2 = dg >> 1;
    int j0 = h ? dg2 : 0, j1 = h ? dg : dg2;
    float4 acc = make_float4(0.f, 0.f, 0.f, 0.f);
    if (h == 0) {
        acc = *(const float4*)&X[(size_t)(ibase + r) * Hc + ln * 4];
        acc.x *= di[r]; acc.y *= di[r]; acc.z *= di[r]; acc.w *= di[r];
    }
    int j = j0;
    for (; j + 8 <= j1; j += 8) {
        float n0 = snrm[r][j],     n1 = snrm[r][j + 1];
        float n2 = snrm[r][j + 2], n3 = snrm[r][j + 3];
        float n4 = snrm[r][j + 4], n5 = snrm[r][j + 5];
        float n6 = snrm[r][j + 6], n7 = snrm[r][j + 7];
        float4 r0 = *(const float4*)&X[sidx[r][j]     + ln * 4];
        float4 r1 = *(const float4*)&X[sidx[r][j + 1] + ln * 4];
        float4 r2 = *(const float4*)&X[sidx[r][j + 2] + ln * 4];
        float4 r3 = *(const float4*)&X[sidx[r][j + 3] + ln * 4];
        float4 r4 = *(const float4*)&X[sidx[r][j + 4] + ln * 4];
        float4 r5 = *(const float4*)&X[sidx[r][j + 5] + ln * 4];
        float4 r6 = *(const float4*)&X[sidx[r][j + 6] + ln * 4];
        float4 r7 = *(const float4*)&X[sidx[r][j + 7] + ln * 4];
        fma4(acc, n0, r0); fma4(acc, n1, r1); fma4(acc, n2, r2); fma4(acc, n3, r3);
        fma4(acc, n4, r4); fma4(acc, n5, r5); fma4(acc, n6, r6); fma4(acc, n7, r7);
    }
    for (; j + 4 <= j1; j += 4) {
        float n0 = snrm[r][j],     n1 = snrm[r][j + 1];
        float n2 = snrm[r][j + 2], n3 = snrm[r][j + 3];
        float4 r0 = *(const float4*)&X[sidx[r][j]     + ln * 4];
        float4 r1 = *(const float4*)&X[sidx[r][j + 1] + ln * 4];
        float4 r2 = *(const float4*)&X[sidx[r][j + 2] + ln * 4];
        float4 r3 = *(const float4*)&X[sidx[r][j + 3] + ln * 4];
        fma4(acc, n0, r0); fma4(acc, n1, r1); fma4(acc, n2, r2); fma4(acc, n3, r3);
    }
    for (; j < j1; j++) {
        float4 r0 = *(const float4*)&X[sidx[r][j] + ln * 4];
        fma4(acc, snrm[r][j], r0);
    }
    *(float4*)&pagg[wv][ln * 4] = acc;
}

// GEMV helper: wave-k-split over Hc rows of W, lane -> 4 cols, inputs packed
// in aggT[k][2], partials to red[wv][node][col].
__device__ __forceinline__ void gemv_wsplit(const float (*aggT)[2],
                                            const float* __restrict__ W,
                                            float (*red)[2][Hc], int t) {
    int wv = t >> 6, ln = t & 63;
    int k0 = wv * (Hc / 4);   // 64 k per wave
    float4 a0 = {0.f, 0.f, 0.f, 0.f}, a1 = {0.f, 0.f, 0.f, 0.f};
    const float* Wp_ = W + (size_t)k0 * Hc + ln * 4;
#pragma unroll 8
    for (int kk = 0; kk < Hc / 4; kk++) {
        float2 g = *(const float2*)&aggT[k0 + kk][0];
        float4 w = *(const float4*)(Wp_ + (size_t)kk * Hc);
        a0.x += g.x * w.x; a0.y += g.x * w.y; a0.z += g.x * w.z; a0.w += g.x * w.w;
        a1.x += g.y * w.x; a1.y += g.y * w.y; a1.z += g.y * w.z; a1.w += g.y * w.w;
    }
    *(float4*)&red[wv][0][ln * 4] = a0;
    *(float4*)&red[wv][1][ln * 4] = a1;
}

// Common head for hidden layers: build sidx/snrm, aggregate, pack aggT.
__device__ __forceinline__ void layer_head(SharedU& su, int b, int t,
        const float* __restrict__ X, const int* __restrict__ cnt,
        const int* __restrict__ colF, int* c, float* di) {
    int ibase = b * 2;
#pragma unroll
    for (int r = 0; r < 2; r++) {
        c[r] = cnt[ibase + r];
        di[r] = rsqrtf((float)(c[r] + 1));
        int deg = min(c[r], CAP);
        if (t < deg) {
            int s = colF[(ibase + r) * CAP + t];
            su.lh.sidx[r][t] = s * Hc;
            su.lh.snrm[r][t] = rsqrtf((float)(cnt[s] + 1));
        }
    }
    __syncthreads();
    agg_wave2(X, su.lh.sidx, su.lh.snrm, c, di, ibase, su.lh.pagg, t);
    __syncthreads();
    *(float2*)&su.lh.aggT[t][0] =
        make_float2(di[0] * (su.lh.pagg[0][t] + su.lh.pagg[1][t]),
                    di[1] * (su.lh.pagg[2][t] + su.lh.pagg[3][t]));
    __syncthreads();
}

// ---------------- middle layer phase: relu(agg(X) @ W + b) -> out --------------
__device__ void phase_lh(SharedU& su, int b, int t,
        const float* __restrict__ X, const float* __restrict__ W,
        const float* __restrict__ bias, const int* __restrict__ cnt,
        const int* __restrict__ colF, float* __restrict__ out) {
    int c[2]; float di[2];
    layer_head(su, b, t, X, cnt, colF, c, di);
    gemv_wsplit(su.lh.aggT, W, su.lh.red, t);
    __syncthreads();
    int ibase = b * 2;
    float bb = bias[t];
    float s0 = (su.lh.red[0][0][t] + su.lh.red[1][0][t]) +
               (su.lh.red[2][0][t] + su.lh.red[3][0][t]) + bb;
    float s1 = (su.lh.red[0][1][t] + su.lh.red[1][1][t]) +
               (su.lh.red[2][1][t] + su.lh.red[3][1][t]) + bb;
    st_wt(&out[(size_t)(ibase + 0) * Hc + t], fmaxf(s0, 0.f));
    st_wt(&out[(size_t)(ibase + 1) * Hc + t], fmaxf(s1, 0.f));
}

// ---------------- last layer + predictor-operand fusion phase ------------------
__device__ void phase_lht(SharedU& su, int b, int t,
        const float* __restrict__ X, const float* __restrict__ W2,
        const float* __restrict__ b2, const int* __restrict__ cnt,
        const int* __restrict__ colF,
        const float* __restrict__ Wup, const float* __restrict__ Wpp,
        const float* __restrict__ bvu, const float* __restrict__ bvp,
        float* __restrict__ AuT, float* __restrict__ ApT) {
    int c[2]; float di[2];
    layer_head(su, b, t, X, cnt, colF, c, di);
    // GEMV 1: x = relu(agg @ W2 + b2) -> xlocT
    gemv_wsplit(su.lh.aggT, W2, su.lh.red, t);
    __syncthreads();
    {
        float bb = b2[t];
        float s0 = (su.lh.red[0][0][t] + su.lh.red[1][0][t]) +
                   (su.lh.red[2][0][t] + su.lh.red[3][0][t]) + bb;
        float s1 = (su.lh.red[0][1][t] + su.lh.red[1][1][t]) +
                   (su.lh.red[2][1][t] + su.lh.red[3][1][t]) + bb;
        *(float2*)&su.lh.xlocT[t][0] = make_float2(fmaxf(s0, 0.f), fmaxf(s1, 0.f));
    }
    __syncthreads();
    // GEMV 2: AuT/ApT[t][rloc..rloc+2] = xloc @ Wsel[:,t] + bsel[t]
    gemv_wsplit(su.lh.xlocT, (b < 256) ? Wup : Wpp, su.lh.red, t);
    __syncthreads();
    {
        int ibase = b * 2;
        const float* bsel = (b < 256) ? bvu : bvp;
        float* YT  = (b < 256) ? AuT : ApT;
        int ldy    = (b < 256) ? Uc : Pc;
        int rloc   = (b < 256) ? ibase : ibase - Uc;
        float bb = bsel[t];
        float s0 = (su.lh.red[0][0][t] + su.lh.red[1][0][t]) +
                   (su.lh.red[2][0][t] + su.lh.red[3][0][t]) + bb;
        float s1 = (su.lh.red[0][1][t] + su.lh.red[1][1][t]) +
                   (su.lh.red[2][1][t] + su.lh.red[3][1][t]) + bb;
        st_wt2(&YT[(size_t)t * ldy + rloc], make_float2(s0, s1));
    }
}

// ---------------- predictor phase ----------------
// Tile: 8 users x 128 papers, 512 blocks. Wave wv -> users 2wv..2wv+1 (LDS
// broadcast); lane -> 2 consecutive papers (float2 coalesced).
__device__ void phase_pred(float* auS, int b, int t,
        const float* __restrict__ AuT, const float* __restrict__ ApT,
        const float* __restrict__ Wq2, const float* __restrict__ bq2,
        float* __restrict__ out) {
    int ub = (b >> 3) * 8, pb = (b & 7) * 128;
#pragma unroll
    for (int i = t; i < Hc * 8; i += 256) {
        int k = i >> 3, u = i & 7;
        auS[i] = AuT[(size_t)k * Uc + ub + u];
    }
    __syncthreads();
    int wv = t >> 6, ln = t & 63;
    const float* app = ApT + pb + ln * 2;
    const float* aup = auS + wv * 2;
    float acc[2][2] = {};
#pragma unroll 4
    for (int k = 0; k < Hc; k++) {
        float w = Wq2[k];                                   // uniform -> s_load
        float2 a = *(const float2*)(aup + k * 8);           // LDS broadcast
        float2 p = *(const float2*)(app + (size_t)k * Pc);  // coalesced 512 B
        acc[0][0] += fmaxf(a.x + p.x, 0.f) * w;
        acc[0][1] += fmaxf(a.x + p.y, 0.f) * w;
        acc[1][0] += fmaxf(a.y + p.x, 0.f) * w;
        acc[1][1] += fmaxf(a.y + p.y, 0.f) * w;
    }
    float bq = bq2[0];
#pragma unroll
    for (int r = 0; r < 2; r++) {
        int u = ub + wv * 2 + r;
        float2 o;
        o.x = 1.f / (1.f + __expf(-(acc[r][0] + bq)));
        o.y = 1.f / (1.f + __expf(-(acc[r][1] + bq)));
        *(float2*)&out[(size_t)u * Pc + pb + ln * 2] = o;
    }
}

// ---------------- fused cooperative kernel ----------------
struct KArgs {
    const int *uid, *pid, *e_src, *e_dst;
    const float *ue, *pe;
    const float *W0, *b0, *W1, *b1, *W2, *b2;
    const float *Wu, *bu, *Wp, *bp, *Wq1, *bq1, *Wq2, *bq2;
    int *cnt, *colF, *bar;
    float *xA, *xB, *Wup, *Wpp, *bvu, *bvp, *AuT, *ApT, *pred;
};

__global__ void __launch_bounds__(256) k_all(KArgs A) {
    __shared__ SharedU su;
    int t = threadIdx.x, b = blockIdx.x;
    // P1: scatter | weight collapse | bias  (cnt zeroed by launcher memset)
    phase_front(b, t, A.e_src, A.e_dst, A.cnt, A.colF, A.Wu, A.Wp, A.Wq1,
                A.bu, A.bp, A.bq1, A.Wup, A.Wpp, A.bvu, A.bvp);
    gbar3(A.bar + 0 * BAR_STRIDE, b);
    // P2-P4: GCN layers
    phase_l0(su, b, t, A.uid, A.pid, A.ue, A.pe, A.W0, A.b0, A.cnt, A.colF, A.xA);
    gbar3(A.bar + 1 * BAR_STRIDE, b);
    phase_lh(su, b, t, A.xA, A.W1, A.b1, A.cnt, A.colF, A.xB);
    gbar3(A.bar + 2 * BAR_STRIDE, b);
    phase_lht(su, b, t, A.xB, A.W2, A.b2, A.cnt, A.colF,
              A.Wup, A.Wpp, A.bvu, A.bvp, A.AuT, A.ApT);
    gbar3(A.bar + 3 * BAR_STRIDE, b);
    // P5: predictor (512 active blocks)
    if (b < 512) phase_pred(su.pr.auS, b, t, A.AuT, A.ApT, A.Wq2, A.bq2, A.pred);
}

// ---------------- standalone kernels (fallback path) ----------------
__global__ void k_front(const int* __restrict__ e_src, const int* __restrict__ e_dst,
                        int* __restrict__ cnt, int* __restrict__ colF,
                        const float* __restrict__ Wu, const float* __restrict__ Wp,
                        const float* __restrict__ Wq1, const float* __restrict__ bu,
                        const float* __restrict__ bp, const float* __restrict__ bq1,
                        float* __restrict__ Wup, float* __restrict__ Wpp,
                        float* __restrict__ bvu, float* __restrict__ bvp) {
    phase_front(blockIdx.x, threadIdx.x, e_src, e_dst, cnt, colF, Wu, Wp, Wq1,
                bu, bp, bq1, Wup, Wpp, bvu, bvp);
}

__global__ void __launch_bounds__(256) k_l0(
        const int* __restrict__ uid, const int* __restrict__ pid,
        const float* __restrict__ ue, const float* __restrict__ pe,
        const float* __restrict__ W0, const float* __restrict__ b0,
        const int* __restrict__ cnt, const int* __restrict__ colF,
        float* __restrict__ out) {
    __shared__ SharedU su;
    phase_l0(su, blockIdx.x, threadIdx.x, uid, pid, ue, pe, W0, b0, cnt, colF, out);
}

__global__ void __launch_bounds__(256) k_lh(
        const float* __restrict__ X, const float* __restrict__ W,
        const float* __restrict__ bias, const int* __restrict__ cnt,
        const int* __restrict__ colF, float* __restrict__ out) {
    __shared__ SharedU su;
    phase_lh(su, blockIdx.x, threadIdx.x, X, W, bias, cnt, colF, out);
}

__global__ void __launch_bounds__(256) k_lht(
        const float* __restrict__ X, const float* __restrict__ W2,
        const float* __restrict__ b2, const int* __restrict__ cnt,
        const int* __restrict__ colF,
        const float* __restrict__ Wup, const float* __restrict__ Wpp,
        const float* __restrict__ bvu, const float* __restrict__ bvp,
        float* __restrict__ AuT, float* __restrict__ ApT) {
    __shared__ SharedU su;
    phase_lht(su, blockIdx.x, threadIdx.x, X, W2, b2, cnt, colF,
              Wup, Wpp, bvu, bvp, AuT, ApT);
}

__global__ void __launch_bounds__(256) k_pred(
        const float* __restrict__ AuT, const float* __restrict__ ApT,
        const float* __restrict__ Wq2, const float* __restrict__ bq2,
        float* __restrict__ out) {
    __shared__ SharedU su;
    phase_pred(su.pr.auS, blockIdx.x, threadIdx.x, AuT, ApT, Wq2, bq2, out);
}

// ---------------- launcher ----------------
extern "C" void kernel_launch(void* const* d_in, const int* in_sizes, int n_in,
                              void* d_out, int out_size, void* d_ws, size_t ws_size,
                              hipStream_t stream) {
    KArgs A;
    A.uid = (const int*)d_in[0];
    A.pid = (const int*)d_in[1];
    const int* ei = (const int*)d_in[2];   // [2,E]: src = ei[0..E), dst = ei[E..2E)
    A.e_src = ei;
    A.e_dst = ei + Ec;
    A.ue  = (const float*)d_in[4];
    A.pe  = (const float*)d_in[5];
    A.W0  = (const float*)d_in[6];  A.b0  = (const float*)d_in[7];
    A.W1  = (const float*)d_in[8];  A.b1  = (const float*)d_in[9];
    A.W2  = (const float*)d_in[10]; A.b2  = (const float*)d_in[11];
    A.Wu  = (const float*)d_in[12]; A.bu  = (const float*)d_in[13];
    A.Wp  = (const float*)d_in[14]; A.bp  = (const float*)d_in[15];
    A.Wq1 = (const float*)d_in[16]; A.bq1 = (const float*)d_in[17];
    A.Wq2 = (const float*)d_in[18]; A.bq2 = (const float*)d_in[19];

    char* w = (char*)d_ws;
    auto alloc = [&](size_t bytes) { char* p = w; w += (bytes + 255) & ~size_t(255); return p; };
    // cnt and barrier counters share one region so a single memset zeroes both.
    constexpr int BAR_BYTES = 4 * BAR_STRIDE * 4;   // 4 barrier instances
    int* zreg = (int*)alloc(Nc * 4 + BAR_BYTES);
    A.cnt  = zreg;
    A.bar  = zreg + Nc;
    A.colF = (int*)alloc((size_t)Nc * CAP * 4);
    A.xA   = (float*)alloc((size_t)Nc * Hc * 4);
    A.xB   = (float*)alloc((size_t)Nc * Hc * 4);
    A.Wup  = (float*)alloc((size_t)Hc * Hc * 4);
    A.Wpp  = (float*)alloc((size_t)Hc * Hc * 4);
    A.bvu  = (float*)alloc(Hc * 4);
    A.bvp  = (float*)alloc(Hc * 4);
    A.AuT  = (float*)alloc((size_t)Hc * Uc * 4);
    A.ApT  = (float*)alloc((size_t)Hc * Pc * 4);
    A.pred = (float*)d_out;

    // 0: zero bucket + barrier counters (tiny DMA)
    hipMemsetAsync(A.cnt, 0, Nc * 4 + BAR_BYTES, stream);

    // Preferred: single fused cooperative kernel with fence-free tree barriers.
    void* kargs[] = { (void*)&A };
    hipError_t err = hipLaunchCooperativeKernel((void*)k_all, dim3(GRID), dim3(256),
                                                kargs, 0, stream);
    if (err == hipSuccess) return;

    // Fallback: proven 6-dispatch path.
    k_front<<<642, 256, 0, stream>>>(A.e_src, A.e_dst, A.cnt, A.colF, A.Wu, A.Wp,
                                     A.Wq1, A.bu, A.bp, A.bq1, A.Wup, A.Wpp,
                                     A.bvu, A.bvp);
    k_l0<<<Nc / 2, 256, 0, stream>>>(A.uid, A.pid, A.ue, A.pe, A.W0, A.b0,
                                     A.cnt, A.colF, A.xA);
    k_lh<<<Nc / 2, 256, 0, stream>>>(A.xA, A.W1, A.b1, A.cnt, A.colF, A.xB);
    k_lht<<<Nc / 2, 256, 0, stream>>>(A.xB, A.W2, A.b2, A.cnt, A.colF,
                                      A.Wup, A.Wpp, A.bvu, A.bvp, A.AuT, A.ApT);
    k_pred<<<512, 256, 0, stream>>>(A.AuT, A.ApT, A.Wq2, A.bq2, A.pred);
}

// Round 7
// 193.947 us; speedup vs baseline: 3.5620x; 1.3211x over previous
//
#include <hip/hip_runtime.h>
#include <math.h>

// Problem constants
constexpr int Uc = 512;
constexpr int Pc = 1024;
constexpr int Dc = 128;
constexpr int Hc = 256;
constexpr int Ec = 98304;
constexpr int Nc = 1536;   // U + P
constexpr int CAP = 192;   // bucket capacity (deg ~ B(98304,1/1536): mu=64, sigma=8)
constexpr int GRID = 768;  // 3 blocks/CU x 256 CUs -> all co-resident
// Barrier instance layout (ints): 64 leaves*16 | 8 mids*16 | root | pad | 64 go*16
constexpr int BAR_STRIDE = 2304;

// ---- write-through agent-scope stores (land at IF; no fence needed later) ----
__device__ __forceinline__ void st_wt(float* p, float v) {
    __hip_atomic_store(p, v, __ATOMIC_RELAXED, __HIP_MEMORY_SCOPE_AGENT);
}
__device__ __forceinline__ void st_wt_i(int* p, int v) {
    __hip_atomic_store(p, v, __ATOMIC_RELAXED, __HIP_MEMORY_SCOPE_AGENT);
}
__device__ __forceinline__ void st_wt2(float* p, float2 v) {
    unsigned long long u;
    __builtin_memcpy(&u, &v, 8);
    __hip_atomic_store((unsigned long long*)p, u, __ATOMIC_RELAXED,
                       __HIP_MEMORY_SCOPE_AGENT);
}

// Fence-free tree grid-barrier (validated round 6: ~15-20 us/sync incl.
// stragglers; ladder flat+fence 115 -> tree+fence 55 -> tree no-fence ~20).
// Cross-phase data is stored write-through (st_wt*), __syncthreads drains
// vmcnt(0) before arrival, and every cross-phase buffer is write-once-then-
// read (first read post-barrier -> L2 miss -> fresh from IF). Arrival:
// 64 leaves -> 8 mids -> root; release: 64 per-leaf go flags (12 pollers
// each). Counters re-zeroed by the launcher's memset every iteration, so
// graph replay re-arms. Timeout valve -> visible fail instead of hang.
__device__ __forceinline__ void gbar3(int* bb, int b) {
    __syncthreads();   // compiler emits s_waitcnt vmcnt(0) before s_barrier
    if (threadIdx.x == 0) {
        int leaf = b & 63;
        int lc = __hip_atomic_fetch_add(bb + leaf * 16, 1,
                                        __ATOMIC_RELAXED, __HIP_MEMORY_SCOPE_AGENT);
        if (lc == 11) {                          // last of 12 blocks on this leaf
            int mc = __hip_atomic_fetch_add(bb + 1024 + (leaf >> 3) * 16, 1,
                                            __ATOMIC_RELAXED, __HIP_MEMORY_SCOPE_AGENT);
            if (mc == 7) {                       // last of 8 leaves in this mid
                int rc = __hip_atomic_fetch_add(bb + 1152, 1,
                                                __ATOMIC_RELAXED, __HIP_MEMORY_SCOPE_AGENT);
                if (rc == 7) {                   // last mid -> broadcast go flags
#pragma unroll
                    for (int i = 0; i < 64; i++)
                        __hip_atomic_store(bb + 1216 + i * 16, 1, __ATOMIC_RELAXED,
                                           __HIP_MEMORY_SCOPE_AGENT);
                }
            }
        }
        int iters = 0;
        while (__hip_atomic_load(bb + 1216 + leaf * 16, __ATOMIC_RELAXED,
                                 __HIP_MEMORY_SCOPE_AGENT) == 0) {
            __builtin_amdgcn_s_sleep(8);         // ~512 cyc backoff, 12 pollers/line
            if (++iters > (1 << 22)) break;      // safety valve -> visible fail
        }
    }
    __syncthreads();
}

__device__ __forceinline__ void fma4(float4& a, float n, const float4 r) {
    a.x += n * r.x; a.y += n * r.y; a.z += n * r.z; a.w += n * r.w;
}

// Shared-memory union: one allocation reused across fused phases (19.5 KB).
union __align__(16) SharedU {
    struct {   // layer 0 (D=128)
        const float* sptr[2][CAP];
        float snrm[2][CAP];
        float pagg[4][Dc];
        float aggT[Dc][2];
        float red[4][2][Hc];
    } l0;
    struct {   // hidden layers (H=256)
        int sidx[2][CAP];
        float snrm[2][CAP];
        float pagg[4][Hc];
        float aggT[Hc][2];
        float xlocT[Hc][2];
        float red[4][2][Hc];
    } lh;
    struct {   // predictor
        float auS[Hc * 8];
    } pr;
};

// ---------------- GEMM core: 16 rows x 32 cols / 256-thread block ----------------
template <int K>
__device__ __forceinline__ void gemm_core16(const float* __restrict__ xr,
                                            const float* __restrict__ wc, int M,
                                            float& acc0, float& acc1) {
#pragma unroll 4
    for (int k = 0; k < K; k += 4) {
        float4 a = *(const float4*)(xr + k);
        float2 b0 = *(const float2*)(wc + (size_t)k * M);
        float2 b1 = *(const float2*)(wc + (size_t)(k + 1) * M);
        float2 b2 = *(const float2*)(wc + (size_t)(k + 2) * M);
        float2 b3 = *(const float2*)(wc + (size_t)(k + 3) * M);
        acc0 += a.x * b0.x; acc1 += a.x * b0.y;
        acc0 += a.y * b1.x; acc1 += a.y * b1.y;
        acc0 += a.z * b2.x; acc1 += a.z * b2.y;
        acc0 += a.w * b3.x; acc1 += a.w * b3.y;
    }
}

// ---------------- front phase: scatter | weight collapse | bias ----------------
__device__ __forceinline__ void phase_front(
        int b, int t,
        const int* __restrict__ e_src, const int* __restrict__ e_dst,
        int* __restrict__ cnt, int* __restrict__ colF,
        const float* __restrict__ Wu, const float* __restrict__ Wp,
        const float* __restrict__ Wq1, const float* __restrict__ bu,
        const float* __restrict__ bp, const float* __restrict__ bq1,
        float* __restrict__ Wup, float* __restrict__ Wpp,
        float* __restrict__ bvu, float* __restrict__ bvp) {
    if (b < 384) {
        int e = b * 256 + t;
        int d = e_dst[e];
        int pos = atomicAdd(&cnt[d], 1);
        if (pos < CAP) st_wt_i(&colF[d * CAP + pos], e_src[e]);
    } else if (b < 640) {
        int id = b - 384;
        int z = id >> 7, tile = id & 127;
        int tx = t & 15, ty = t >> 4;
        const float* X = z ? Wp : Wu;
        const float* W = Wq1 + (z ? (size_t)Dc * Hc : 0);
        float* Y = z ? Wpp : Wup;
        int row = (tile >> 3) * 16 + ty, col = (tile & 7) * 32 + tx * 2;
        float a0 = 0.f, a1 = 0.f;
        gemm_core16<Dc>(X + (size_t)row * Dc, W + col, Hc, a0, a1);
        st_wt2(&Y[(size_t)row * Hc + col], make_float2(a0, a1));
    } else if (b == 640) {
        float s = bq1[t];
#pragma unroll 8
        for (int d = 0; d < Dc; d++) s += bu[d] * Wq1[d * Hc + t];
        st_wt(&bvu[t], s);
    } else if (b == 641) {
        float s = 0.f;
#pragma unroll 8
        for (int d = 0; d < Dc; d++) s += bp[d] * Wq1[(Dc + d) * Hc + t];
        st_wt(&bvp[t], s);
    }
}

// ---------------- layer 0 phase: agg(embeddings) @ W0 + b0, relu -> xA ---------
// 2 nodes / block (768 blocks). Waves (2r, 2r+1) aggregate node r over neighbor
// halves; lane l -> features 2l..2l+2 (D=128). GEMV wave-k-split, float4 W.
__device__ void phase_l0(SharedU& su, int b, int t,
        const int* __restrict__ uid, const int* __restrict__ pid,
        const float* __restrict__ ue, const float* __restrict__ pe,
        const float* __restrict__ W0, const float* __restrict__ b0,
        const int* __restrict__ cnt, const int* __restrict__ colF,
        float* __restrict__ out) {
    int ibase = b * 2;
    int c[2]; float di[2];
#pragma unroll
    for (int r = 0; r < 2; r++) {
        c[r] = cnt[ibase + r];
        di[r] = rsqrtf((float)(c[r] + 1));
        int deg = min(c[r], CAP);
        if (t < deg) {
            int s = colF[(ibase + r) * CAP + t];
            su.l0.sptr[r][t] = (s < Uc) ? ue + (size_t)uid[s] * Dc
                                        : pe + (size_t)pid[s - Uc] * Dc;
            su.l0.snrm[r][t] = rsqrtf((float)(cnt[s] + 1));
        }
    }
    __syncthreads();
    {   // wave wv: node r = wv>>1, neighbor half h = wv&1
        int wv = t >> 6, ln = t & 63;
        int r = wv >> 1, h = wv & 1;
        int i = ibase + r;
        int dg = min(c[r], CAP);
        int dg2 = dg >> 1;
        int j0 = h ? dg2 : 0, j1 = h ? dg : dg2;
        float2 acc = make_float2(0.f, 0.f);
        if (h == 0) {
            const float* xi = (i < Uc) ? ue + (size_t)uid[i] * Dc
                                       : pe + (size_t)pid[i - Uc] * Dc;
            float2 a2 = *(const float2*)(xi + ln * 2);
            acc.x = di[r] * a2.x;
            acc.y = di[r] * a2.y;
        }
        int j = j0;
        for (; j + 8 <= j1; j += 8) {
            float n0 = su.l0.snrm[r][j],     n1 = su.l0.snrm[r][j + 1];
            float n2 = su.l0.snrm[r][j + 2], n3 = su.l0.snrm[r][j + 3];
            float n4 = su.l0.snrm[r][j + 4], n5 = su.l0.snrm[r][j + 5];
            float n6 = su.l0.snrm[r][j + 6], n7 = su.l0.snrm[r][j + 7];
            float2 r0 = *(const float2*)(su.l0.sptr[r][j]     + ln * 2);
            float2 r1 = *(const float2*)(su.l0.sptr[r][j + 1] + ln * 2);
            float2 r2 = *(const float2*)(su.l0.sptr[r][j + 2] + ln * 2);
            float2 r3 = *(const float2*)(su.l0.sptr[r][j + 3] + ln * 2);
            float2 r4 = *(const float2*)(su.l0.sptr[r][j + 4] + ln * 2);
            float2 r5 = *(const float2*)(su.l0.sptr[r][j + 5] + ln * 2);
            float2 r6 = *(const float2*)(su.l0.sptr[r][j + 6] + ln * 2);
            float2 r7 = *(const float2*)(su.l0.sptr[r][j + 7] + ln * 2);
            acc.x += n0 * r0.x + n1 * r1.x + n2 * r2.x + n3 * r3.x;
            acc.y += n0 * r0.y + n1 * r1.y + n2 * r2.y + n3 * r3.y;
            acc.x += n4 * r4.x + n5 * r5.x + n6 * r6.x + n7 * r7.x;
            acc.y += n4 * r4.y + n5 * r5.y + n6 * r6.y + n7 * r7.y;
        }
        for (; j + 4 <= j1; j += 4) {
            float n0 = su.l0.snrm[r][j],     n1 = su.l0.snrm[r][j + 1];
            float n2 = su.l0.snrm[r][j + 2], n3 = su.l0.snrm[r][j + 3];
            float2 r0 = *(const float2*)(su.l0.sptr[r][j]     + ln * 2);
            float2 r1 = *(const float2*)(su.l0.sptr[r][j + 1] + ln * 2);
            float2 r2 = *(const float2*)(su.l0.sptr[r][j + 2] + ln * 2);
            float2 r3 = *(const float2*)(su.l0.sptr[r][j + 3] + ln * 2);
            acc.x += n0 * r0.x + n1 * r1.x + n2 * r2.x + n3 * r3.x;
            acc.y += n0 * r0.y + n1 * r1.y + n2 * r2.y + n3 * r3.y;
        }
        for (; j < j1; j++) {
            float2 r0 = *(const float2*)(su.l0.sptr[r][j] + ln * 2);
            acc.x += su.l0.snrm[r][j] * r0.x;
            acc.y += su.l0.snrm[r][j] * r0.y;
        }
        su.l0.pagg[wv][ln * 2]     = acc.x;
        su.l0.pagg[wv][ln * 2 + 1] = acc.y;
    }
    __syncthreads();
    {   // combine halves: thread -> (node r = t>>7, feature f = t&127), packed [f][r]
        int r = t >> 7, f = t & 127;
        su.l0.aggT[f][r] = di[r] * (su.l0.pagg[2 * r][f] + su.l0.pagg[2 * r + 1][f]);
    }
    __syncthreads();
    {   // GEMV: wave-k-split, lane -> 4 cols, W0 as float4
        int wv = t >> 6, ln = t & 63;
        int k0 = wv * (Dc / 4);   // 32 k per wave
        float4 a0 = {0.f, 0.f, 0.f, 0.f}, a1 = {0.f, 0.f, 0.f, 0.f};
        const float* Wp_ = W0 + (size_t)k0 * Hc + ln * 4;
#pragma unroll 8
        for (int kk = 0; kk < Dc / 4; kk++) {
            float2 g = *(const float2*)&su.l0.aggT[k0 + kk][0];
            float4 w = *(const float4*)(Wp_ + (size_t)kk * Hc);
            a0.x += g.x * w.x; a0.y += g.x * w.y; a0.z += g.x * w.z; a0.w += g.x * w.w;
            a1.x += g.y * w.x; a1.y += g.y * w.y; a1.z += g.y * w.z; a1.w += g.y * w.w;
        }
        *(float4*)&su.l0.red[wv][0][ln * 4] = a0;
        *(float4*)&su.l0.red[wv][1][ln * 4] = a1;
    }
    __syncthreads();
    {
        float bb = b0[t];
        float s0 = (su.l0.red[0][0][t] + su.l0.red[1][0][t]) +
                   (su.l0.red[2][0][t] + su.l0.red[3][0][t]) + bb;
        float s1 = (su.l0.red[0][1][t] + su.l0.red[1][1][t]) +
                   (su.l0.red[2][1][t] + su.l0.red[3][1][t]) + bb;
        st_wt(&out[(size_t)(ibase + 0) * Hc + t], fmaxf(s0, 0.f));
        st_wt(&out[(size_t)(ibase + 1) * Hc + t], fmaxf(s1, 0.f));
    }
}

// Wave-pair H-dim aggregation for 2 nodes: wave wv -> (node wv>>1, half wv&1),
// lane l -> 4 features. Partials to pagg; caller combines.
__device__ __forceinline__ void agg_wave2(const float* __restrict__ X,
                                          const int (*sidx)[CAP], const float (*snrm)[CAP],
                                          const int* c, const float* di, int ibase,
                                          float (*pagg)[Hc], int t) {
    int wv = t >> 6, ln = t & 63;
    int r = wv >> 1, h = wv & 1;
    int dg = min(c[r], CAP);
    int dg2 = dg >> 1;
    int j0 = h ? dg2 : 0, j1 = h ? dg : dg2;
    float4 acc = make_float4(0.f, 0.f, 0.f, 0.f);
    if (h == 0) {
        acc = *(const float4*)&X[(size_t)(ibase + r) * Hc + ln * 4];
        acc.x *= di[r]; acc.y *= di[r]; acc.z *= di[r]; acc.w *= di[r];
    }
    int j = j0;
    for (; j + 8 <= j1; j += 8) {
        float n0 = snrm[r][j],     n1 = snrm[r][j + 1];
        float n2 = snrm[r][j + 2], n3 = snrm[r][j + 3];
        float n4 = snrm[r][j + 4], n5 = snrm[r][j + 5];
        float n6 = snrm[r][j + 6], n7 = snrm[r][j + 7];
        float4 r0 = *(const float4*)&X[sidx[r][j]     + ln * 4];
        float4 r1 = *(const float4*)&X[sidx[r][j + 1] + ln * 4];
        float4 r2 = *(const float4*)&X[sidx[r][j + 2] + ln * 4];
        float4 r3 = *(const float4*)&X[sidx[r][j + 3] + ln * 4];
        float4 r4 = *(const float4*)&X[sidx[r][j + 4] + ln * 4];
        float4 r5 = *(const float4*)&X[sidx[r][j + 5] + ln * 4];
        float4 r6 = *(const float4*)&X[sidx[r][j + 6] + ln * 4];
        float4 r7 = *(const float4*)&X[sidx[r][j + 7] + ln * 4];
        fma4(acc, n0, r0); fma4(acc, n1, r1); fma4(acc, n2, r2); fma4(acc, n3, r3);
        fma4(acc, n4, r4); fma4(acc, n5, r5); fma4(acc, n6, r6); fma4(acc, n7, r7);
    }
    for (; j + 4 <= j1; j += 4) {
        float n0 = snrm[r][j],     n1 = snrm[r][j + 1];
        float n2 = snrm[r][j + 2], n3 = snrm[r][j + 3];
        float4 r0 = *(const float4*)&X[sidx[r][j]     + ln * 4];
        float4 r1 = *(const float4*)&X[sidx[r][j + 1] + ln * 4];
        float4 r2 = *(const float4*)&X[sidx[r][j + 2] + ln * 4];
        float4 r3 = *(const float4*)&X[sidx[r][j + 3] + ln * 4];
        fma4(acc, n0, r0); fma4(acc, n1, r1); fma4(acc, n2, r2); fma4(acc, n3, r3);
    }
    for (; j < j1; j++) {
        float4 r0 = *(const float4*)&X[sidx[r][j] + ln * 4];
        fma4(acc, snrm[r][j], r0);
    }
    *(float4*)&pagg[wv][ln * 4] = acc;
}

// GEMV helper: wave-k-split over Hc rows of W, lane -> 4 cols, inputs packed
// in aggT[k][2], partials to red[wv][node][col].
__device__ __forceinline__ void gemv_wsplit(const float (*aggT)[2],
                                            const float* __restrict__ W,
                                            float (*red)[2][Hc], int t) {
    int wv = t >> 6, ln = t & 63;
    int k0 = wv * (Hc / 4);   // 64 k per wave
    float4 a0 = {0.f, 0.f, 0.f, 0.f}, a1 = {0.f, 0.f, 0.f, 0.f};
    const float* Wp_ = W + (size_t)k0 * Hc + ln * 4;
#pragma unroll 8
    for (int kk = 0; kk < Hc / 4; kk++) {
        float2 g = *(const float2*)&aggT[k0 + kk][0];
        float4 w = *(const float4*)(Wp_ + (size_t)kk * Hc);
        a0.x += g.x * w.x; a0.y += g.x * w.y; a0.z += g.x * w.z; a0.w += g.x * w.w;
        a1.x += g.y * w.x; a1.y += g.y * w.y; a1.z += g.y * w.z; a1.w += g.y * w.w;
    }
    *(float4*)&red[wv][0][ln * 4] = a0;
    *(float4*)&red[wv][1][ln * 4] = a1;
}

// Common head for hidden layers: build sidx/snrm, aggregate, pack aggT.
__device__ __forceinline__ void layer_head(SharedU& su, int b, int t,
        const float* __restrict__ X, const int* __restrict__ cnt,
        const int* __restrict__ colF, int* c, float* di) {
    int ibase = b * 2;
#pragma unroll
    for (int r = 0; r < 2; r++) {
        c[r] = cnt[ibase + r];
        di[r] = rsqrtf((float)(c[r] + 1));
        int deg = min(c[r], CAP);
        if (t < deg) {
            int s = colF[(ibase + r) * CAP + t];
            su.lh.sidx[r][t] = s * Hc;
            su.lh.snrm[r][t] = rsqrtf((float)(cnt[s] + 1));
        }
    }
    __syncthreads();
    agg_wave2(X, su.lh.sidx, su.lh.snrm, c, di, ibase, su.lh.pagg, t);
    __syncthreads();
    *(float2*)&su.lh.aggT[t][0] =
        make_float2(di[0] * (su.lh.pagg[0][t] + su.lh.pagg[1][t]),
                    di[1] * (su.lh.pagg[2][t] + su.lh.pagg[3][t]));
    __syncthreads();
}

// ---------------- middle layer phase: relu(agg(X) @ W + b) -> out --------------
__device__ void phase_lh(SharedU& su, int b, int t,
        const float* __restrict__ X, const float* __restrict__ W,
        const float* __restrict__ bias, const int* __restrict__ cnt,
        const int* __restrict__ colF, float* __restrict__ out) {
    int c[2]; float di[2];
    layer_head(su, b, t, X, cnt, colF, c, di);
    gemv_wsplit(su.lh.aggT, W, su.lh.red, t);
    __syncthreads();
    int ibase = b * 2;
    float bb = bias[t];
    float s0 = (su.lh.red[0][0][t] + su.lh.red[1][0][t]) +
               (su.lh.red[2][0][t] + su.lh.red[3][0][t]) + bb;
    float s1 = (su.lh.red[0][1][t] + su.lh.red[1][1][t]) +
               (su.lh.red[2][1][t] + su.lh.red[3][1][t]) + bb;
    st_wt(&out[(size_t)(ibase + 0) * Hc + t], fmaxf(s0, 0.f));
    st_wt(&out[(size_t)(ibase + 1) * Hc + t], fmaxf(s1, 0.f));
}

// ---------------- last layer + predictor-operand fusion phase ------------------
__device__ void phase_lht(SharedU& su, int b, int t,
        const float* __restrict__ X, const float* __restrict__ W2,
        const float* __restrict__ b2, const int* __restrict__ cnt,
        const int* __restrict__ colF,
        const float* __restrict__ Wup, const float* __restrict__ Wpp,
        const float* __restrict__ bvu, const float* __restrict__ bvp,
        float* __restrict__ AuT, float* __restrict__ ApT) {
    int c[2]; float di[2];
    layer_head(su, b, t, X, cnt, colF, c, di);
    // GEMV 1: x = relu(agg @ W2 + b2) -> xlocT
    gemv_wsplit(su.lh.aggT, W2, su.lh.red, t);
    __syncthreads();
    {
        float bb = b2[t];
        float s0 = (su.lh.red[0][0][t] + su.lh.red[1][0][t]) +
                   (su.lh.red[2][0][t] + su.lh.red[3][0][t]) + bb;
        float s1 = (su.lh.red[0][1][t] + su.lh.red[1][1][t]) +
                   (su.lh.red[2][1][t] + su.lh.red[3][1][t]) + bb;
        *(float2*)&su.lh.xlocT[t][0] = make_float2(fmaxf(s0, 0.f), fmaxf(s1, 0.f));
    }
    __syncthreads();
    // GEMV 2: AuT/ApT[t][rloc..rloc+2] = xloc @ Wsel[:,t] + bsel[t]
    gemv_wsplit(su.lh.xlocT, (b < 256) ? Wup : Wpp, su.lh.red, t);
    __syncthreads();
    {
        int ibase = b * 2;
        const float* bsel = (b < 256) ? bvu : bvp;
        float* YT  = (b < 256) ? AuT : ApT;
        int ldy    = (b < 256) ? Uc : Pc;
        int rloc   = (b < 256) ? ibase : ibase - Uc;
        float bb = bsel[t];
        float s0 = (su.lh.red[0][0][t] + su.lh.red[1][0][t]) +
                   (su.lh.red[2][0][t] + su.lh.red[3][0][t]) + bb;
        float s1 = (su.lh.red[0][1][t] + su.lh.red[1][1][t]) +
                   (su.lh.red[2][1][t] + su.lh.red[3][1][t]) + bb;
        st_wt2(&YT[(size_t)t * ldy + rloc], make_float2(s0, s1));
    }
}

// ---------------- predictor phase ----------------
// Tile: 8 users x 128 papers, 512 blocks. Wave wv -> users 2wv..2wv+1 (LDS
// broadcast); lane -> 2 consecutive papers (float2 coalesced).
__device__ void phase_pred(float* auS, int b, int t,
        const float* __restrict__ AuT, const float* __restrict__ ApT,
        const float* __restrict__ Wq2, const float* __restrict__ bq2,
        float* __restrict__ out) {
    int ub = (b >> 3) * 8, pb = (b & 7) * 128;
#pragma unroll
    for (int i = t; i < Hc * 8; i += 256) {
        int k = i >> 3, u = i & 7;
        auS[i] = AuT[(size_t)k * Uc + ub + u];
    }
    __syncthreads();
    int wv = t >> 6, ln = t & 63;
    const float* app = ApT + pb + ln * 2;
    const float* aup = auS + wv * 2;
    float acc[2][2] = {};
#pragma unroll 4
    for (int k = 0; k < Hc; k++) {
        float w = Wq2[k];                                   // uniform -> s_load
        float2 a = *(const float2*)(aup + k * 8);           // LDS broadcast
        float2 p = *(const float2*)(app + (size_t)k * Pc);  // coalesced 512 B
        acc[0][0] += fmaxf(a.x + p.x, 0.f) * w;
        acc[0][1] += fmaxf(a.x + p.y, 0.f) * w;
        acc[1][0] += fmaxf(a.y + p.x, 0.f) * w;
        acc[1][1] += fmaxf(a.y + p.y, 0.f) * w;
    }
    float bq = bq2[0];
#pragma unroll
    for (int r = 0; r < 2; r++) {
        int u = ub + wv * 2 + r;
        float2 o;
        o.x = 1.f / (1.f + __expf(-(acc[r][0] + bq)));
        o.y = 1.f / (1.f + __expf(-(acc[r][1] + bq)));
        *(float2*)&out[(size_t)u * Pc + pb + ln * 2] = o;
    }
}

// ---------------- fused kernel (regular launch; grid <= device capacity) -------
struct KArgs {
    const int *uid, *pid, *e_src, *e_dst;
    const float *ue, *pe;
    const float *W0, *b0, *W1, *b1, *W2, *b2;
    const float *Wu, *bu, *Wp, *bp, *Wq1, *bq1, *Wq2, *bq2;
    int *cnt, *colF, *bar;
    float *xA, *xB, *Wup, *Wpp, *bvu, *bvp, *AuT, *ApT, *pred;
};

// Co-residency: 768 blocks x (19456 B LDS, 60 VGPR, 4 waves) = 3 blocks/CU on
// 256 CUs (LDS allows 8, VGPR 8+). Regular launch -> graph-capturable, saving
// the ~125 us hipLaunchCooperativeKernel dispatch overhead measured r3-r6.
__global__ void __launch_bounds__(256) k_all(KArgs A) {
    __shared__ SharedU su;
    int t = threadIdx.x, b = blockIdx.x;
    // P1: scatter | weight collapse | bias  (cnt zeroed by launcher memset)
    phase_front(b, t, A.e_src, A.e_dst, A.cnt, A.colF, A.Wu, A.Wp, A.Wq1,
                A.bu, A.bp, A.bq1, A.Wup, A.Wpp, A.bvu, A.bvp);
    gbar3(A.bar + 0 * BAR_STRIDE, b);
    // P2-P4: GCN layers
    phase_l0(su, b, t, A.uid, A.pid, A.ue, A.pe, A.W0, A.b0, A.cnt, A.colF, A.xA);
    gbar3(A.bar + 1 * BAR_STRIDE, b);
    phase_lh(su, b, t, A.xA, A.W1, A.b1, A.cnt, A.colF, A.xB);
    gbar3(A.bar + 2 * BAR_STRIDE, b);
    phase_lht(su, b, t, A.xB, A.W2, A.b2, A.cnt, A.colF,
              A.Wup, A.Wpp, A.bvu, A.bvp, A.AuT, A.ApT);
    gbar3(A.bar + 3 * BAR_STRIDE, b);
    // P5: predictor (512 active blocks)
    if (b < 512) phase_pred(su.pr.auS, b, t, A.AuT, A.ApT, A.Wq2, A.bq2, A.pred);
}

// ---------------- launcher ----------------
extern "C" void kernel_launch(void* const* d_in, const int* in_sizes, int n_in,
                              void* d_out, int out_size, void* d_ws, size_t ws_size,
                              hipStream_t stream) {
    KArgs A;
    A.uid = (const int*)d_in[0];
    A.pid = (const int*)d_in[1];
    const int* ei = (const int*)d_in[2];   // [2,E]: src = ei[0..E), dst = ei[E..2E)
    A.e_src = ei;
    A.e_dst = ei + Ec;
    A.ue  = (const float*)d_in[4];
    A.pe  = (const float*)d_in[5];
    A.W0  = (const float*)d_in[6];  A.b0  = (const float*)d_in[7];
    A.W1  = (const float*)d_in[8];  A.b1  = (const float*)d_in[9];
    A.W2  = (const float*)d_in[10]; A.b2  = (const float*)d_in[11];
    A.Wu  = (const float*)d_in[12]; A.bu  = (const float*)d_in[13];
    A.Wp  = (const float*)d_in[14]; A.bp  = (const float*)d_in[15];
    A.Wq1 = (const float*)d_in[16]; A.bq1 = (const float*)d_in[17];
    A.Wq2 = (const float*)d_in[18]; A.bq2 = (const float*)d_in[19];

    char* w = (char*)d_ws;
    auto alloc = [&](size_t bytes) { char* p = w; w += (bytes + 255) & ~size_t(255); return p; };
    // cnt and barrier counters share one region so a single memset zeroes both
    // every iteration (graph replay re-arms the barriers).
    constexpr int BAR_BYTES = 4 * BAR_STRIDE * 4;   // 4 barrier instances
    int* zreg = (int*)alloc(Nc * 4 + BAR_BYTES);
    A.cnt  = zreg;
    A.bar  = zreg + Nc;
    A.colF = (int*)alloc((size_t)Nc * CAP * 4);
    A.xA   = (float*)alloc((size_t)Nc * Hc * 4);
    A.xB   = (float*)alloc((size_t)Nc * Hc * 4);
    A.Wup  = (float*)alloc((size_t)Hc * Hc * 4);
    A.Wpp  = (float*)alloc((size_t)Hc * Hc * 4);
    A.bvu  = (float*)alloc(Hc * 4);
    A.bvp  = (float*)alloc(Hc * 4);
    A.AuT  = (float*)alloc((size_t)Hc * Uc * 4);
    A.ApT  = (float*)alloc((size_t)Hc * Pc * 4);
    A.pred = (float*)d_out;

    // 0: zero bucket + barrier counters (tiny DMA)
    hipMemsetAsync(A.cnt, 0, Nc * 4 + BAR_BYTES, stream);
    // 1: single fused kernel, regular (graph-capturable) launch
    k_all<<<GRID, 256, 0, stream>>>(A);
}